// Round 12
// baseline (336.870 us; speedup 1.0000x reference)
//
#include <hip/hip_runtime.h>

// KacLayer: out[512][4096] = x @ W^T + b  +  Kac2( vec * Kac1( x ) )
//
//  kfused: blocks 0..11: per-8192-step window scheduler. Election assigns
//          dependency depth; one-shot level layout with +3 gap chunks between
//          non-empty levels => column-sharing steps >=4 chunks apart => any 4
//          consecutive chunks column-disjoint (pad records are idempotent,
//          identity on slots 4096/4097). Records scattered to global
//          (pad-prefilled). Bit-exact reorder of commuting Givens rotations.
//          blocks 12..1163: fp32->bf16 convert of W and X into d_ws.
//  kgemm_bf: bf16 MFMA GEMM, 128x128 tile, BK=128, XOR-swizzled LDS,
//          runtime Ksplit (4 if ws allows, else 2) -> out + (nks-1) partials.
//  kwalk : 128 thr/block, each wave owns ONE private float row in LDS.
//          PAIR pipeline: each iteration processes 2 chunks (4 records/lane);
//          raw records ring-buffered 3 pairs deep + 1 pair in flight (load
//          issued 4 pair-iterations before decode -> L2 latency fully hidden);
//          decode+gather pair p+1 issued before scatter pair p (safe by the
//          4-consecutive-chunk disjointness; in-order per-wave DS pipe).

#define DIM    4096
#define ROWS   512
#define NSTEPS 49152
#define WSTEPS 8192
#define NW2    (NSTEPS / WSTEPS)   // 6 windows per walk
#define NSLOT  (2 * NW2)           // 12 slots
#define MAXCHP 256
#define NSG    16                  // rank subgroups (one per wave)
#define CHUNK  128
#define SLOT   (MAXCHP * CHUNK)    // 32768 records per slot
#define MAXR   96
#define PADI   4096
#define PADJ   4097
#define KT     1024                // scheduler threads
#define SPT    (WSTEPS / KT)       // 8 steps per thread
#define NCVW   1024                // W-convert blocks
#define NCVX   128                 // X-convert blocks

typedef short  short8 __attribute__((ext_vector_type(8)));
typedef __bf16 bf16x8 __attribute__((ext_vector_type(8)));
typedef float  f32x4  __attribute__((ext_vector_type(4)));

__device__ inline short f2bf(float f) {
    unsigned u = __builtin_bit_cast(unsigned, f);
    u += 0x7FFFu + ((u >> 16) & 1u);
    return (short)(u >> 16);
}
__device__ inline short8 pack8(float4 a, float4 b) {
    short8 r;
    r[0] = f2bf(a.x); r[1] = f2bf(a.y); r[2] = f2bf(a.z); r[3] = f2bf(a.w);
    r[4] = f2bf(b.x); r[5] = f2bf(b.y); r[6] = f2bf(b.z); r[7] = f2bf(b.w);
    return r;
}
__device__ inline float bitf(unsigned u) { return __builtin_bit_cast(float, u); }
__device__ inline float ldf(const float* rw, int boff) {
    return *(const float*)((const char*)rw + boff);
}
__device__ inline void stf(float* rw, int boff, float v) {
    *(float*)((char*)rw + boff) = v;
}

// ---------------------------------------------------------------------------
// 1) fused scheduler (blocks 0..NSLOT-1) + bf16 convert (blocks NSLOT..)
// ---------------------------------------------------------------------------
__global__ __launch_bounds__(KT) void kfused(
    const int* __restrict__ i1, const int* __restrict__ j1,
    const float* __restrict__ c1, const float* __restrict__ s1,
    const int* __restrict__ i2, const int* __restrict__ j2,
    const float* __restrict__ c2, const float* __restrict__ s2,
    uint4* __restrict__ recs, int* __restrict__ cnts,
    int doconv, const float* __restrict__ W, const float* __restrict__ X,
    short* __restrict__ wb, short* __restrict__ xb) {

    // ---------------- convert path ----------------
    if (blockIdx.x >= NSLOT) {
        if (!doconv) return;
        const int cb = blockIdx.x - NSLOT;
        const float* src; short* dst; size_t base;
        if (cb < NCVW) { src = W; dst = wb; base = (size_t)cb * 16384; }
        else           { src = X; dst = xb; base = (size_t)(cb - NCVW) * 16384; }
        const size_t o = base + (size_t)threadIdx.x * 16;
        const float4* s4 = (const float4*)(src + o);
        const float4 a0 = s4[0], a1 = s4[1], a2 = s4[2], a3 = s4[3];
        *(short8*)(dst + o)     = pack8(a0, a1);
        *(short8*)(dst + o + 8) = pack8(a2, a3);
        return;
    }

    // ---------------- scheduler path ----------------
    __shared__ unsigned tbl[DIM];          // election keys      (16 KB)
    __shared__ unsigned spair[WSTEPS];     // li | lj<<16        (32 KB)
    __shared__ unsigned lvrk[WSTEPS];      // rank<<8 | level    (32 KB)
    __shared__ int lcnt[MAXR * NSG];       // per-(level,wave) counters (6 KB)
    __shared__ int ltot[MAXR], chbase[MAXR];
    __shared__ int nchunks;

    const int b    = blockIdx.x;           // 0..11
    const int walk = b / NW2;
    const int w    = b % NW2;
    const int t    = threadIdx.x;
    const int gb   = w * WSTEPS;
    const int sg   = t >> 6;               // wave id 0..15

    const int*   I = walk ? i2 : i1;
    const int*   J = walk ? j2 : j1;
    const float* C = walk ? c2 : c1;
    const float* S = walk ? s2 : s1;

    uint4* slotp = recs + (size_t)b * SLOT;

    // prefill slot region with identity-pad records (coalesced)
    {
        const uint4 padrec = { (unsigned)(PADI * 4), 0x3F800000u, 0u, (unsigned)(PADJ * 4) };
        for (int k = t; k < SLOT; k += KT) slotp[k] = padrec;
    }
    for (int s = t; s < WSTEPS; s += KT)
        spair[s] = (unsigned)I[gb + s] | ((unsigned)J[gb + s] << 16);
    for (int k = t; k < DIM; k += KT) tbl[k] = 0xFFFFFFFFu;
    for (int k = t; k < MAXR * NSG; k += KT) lcnt[k] = 0;
    __syncthreads();

    // ---- election: 2 barriers/round; level = DAG depth --------------------
    unsigned pmask = (1u << SPT) - 1u;
    for (int rr = 0; rr < MAXR; ++rr) {
        const unsigned rk = (unsigned)(MAXR - 1 - rr) << 13;
#pragma unroll
        for (int q = 0; q < SPT; ++q)
            if (pmask & (1u << q)) {
                const int s = q * KT + t;
                const unsigned sp = spair[s];
                const unsigned key = rk | (unsigned)s;
                atomicMin(&tbl[sp & 0xFFFFu], key);
                atomicMin(&tbl[sp >> 16], key);
            }
        __syncthreads();                                   // B1
#pragma unroll
        for (int q = 0; q < SPT; ++q)
            if (pmask & (1u << q)) {
                const int s = q * KT + t;
                const unsigned sp = spair[s];
                const unsigned key = rk | (unsigned)s;
                if (tbl[sp & 0xFFFFu] == key && tbl[sp >> 16] == key) {
                    const int rank = atomicAdd(&lcnt[rr * NSG + sg], 1);
                    lvrk[s] = ((unsigned)rank << 8) | (unsigned)rr;
                    pmask &= ~(1u << q);
                }
            }
        const int np = __syncthreads_count(pmask != 0);    // B2
        if (np == 0) break;
    }
    // safety net (statistically unreachable)
#pragma unroll
    for (int q = 0; q < SPT; ++q)
        if (pmask & (1u << q)) {
            const int s = q * KT + t;
            const int rank = atomicAdd(&lcnt[(MAXR - 1) * NSG + sg], 1);
            lvrk[s] = ((unsigned)rank << 8) | (unsigned)(MAXR - 1);
        }
    __syncthreads();

    // ---- one-shot layout: level r -> ceil(cnt/128) chunks + 3 gap chunks --
    if (t < MAXR) {
        int run = 0;
        for (int g = 0; g < NSG; ++g) {
            const int v = lcnt[t * NSG + g];
            lcnt[t * NSG + g] = run;
            run += v;
        }
        ltot[t] = run;
    }
    __syncthreads();
    if (t < 64) {
        const int l = t;
        const int tot1 = ltot[l];
        const int w1 = (tot1 > 0) ? (((tot1 + 127) >> 7) + 3) : 0;
        int x1 = w1;
        for (int off = 1; off < 64; off <<= 1) {
            const int v = __shfl_up(x1, off);
            if (l >= off) x1 += v;
        }
        chbase[l] = x1 - w1;
        const int seg1 = __shfl(x1, 63);
        const int l2 = 64 + (l & 31);
        const int tot2 = ltot[l2];
        const int w2 = (tot2 > 0) ? (((tot2 + 127) >> 7) + 3) : 0;
        int x2 = w2;
        for (int off = 1; off < 32; off <<= 1) {
            const int v = __shfl_up(x2, off);
            if ((l & 31) >= off) x2 += v;
        }
        if (l < 32) chbase[l2] = seg1 + x2 - w2;
        if (l == 31) nchunks = seg1 + x2;
    }
    __syncthreads();
    if (t == 0) {
        int nc = nchunks;
        if (nc < 8) nc = 8;
        nc = (nc + 1) & ~1;                 // even (pair processing)
        if (nc > MAXCHP) nc = MAXCHP;
        cnts[b] = nc * CHUNK;
    }

    // ---- record emission (float byte offsets = idx*4) ---------------------
#pragma unroll
    for (int q = 0; q < SPT; ++q) {
        const int s = q * KT + t;
        const unsigned v = lvrk[s];
        const int lvl  = (int)(v & 0xFFu);
        const int rank = (int)(v >> 8) + lcnt[lvl * NSG + sg];
        const int p    = (chbase[lvl] + (rank >> 7)) * CHUNK + (rank & 127);
        if (p < SLOT) {
            const unsigned sp = spair[s];
            const int g = gb + s;
            uint4 r;
            r.x = (sp & 0xFFFFu) * 4u;
            r.y = __builtin_bit_cast(unsigned, C[g]);
            r.z = __builtin_bit_cast(unsigned, S[g]);
            r.w = (sp >> 16) * 4u;
            slotp[p] = r;
        }
    }
}

// ---------------------------------------------------------------------------
// 2a) bf16 GEMM: 128x128 tile, BK=128, runtime Ksplit nks
// ---------------------------------------------------------------------------
__global__ __launch_bounds__(256) void kgemm_bf(const short* __restrict__ Xb, const short* __restrict__ Wb,
                                                const float* __restrict__ bias, float* __restrict__ out,
                                                float* __restrict__ parts, int nks) {
    __shared__ short As[128 * 128];
    __shared__ short Bs[128 * 128];
    const int bid  = blockIdx.x;
    const int ks   = bid % nks;
    const int tile = bid / nks;                // 0..127
    const int bm   = (tile >> 5) * 128;
    const int bn   = (tile & 31) * 128;
    const int tid  = threadIdx.x;
    const int lane = tid & 63;
    const int wv   = tid >> 6;
    const int wr   = (wv >> 1) * 64;
    const int wc   = (wv & 1) * 64;
    const int fr   = lane & 15;
    const int ke   = (lane >> 4) * 8;

    f32x4 acc[4][4];
#pragma unroll
    for (int m = 0; m < 4; ++m)
#pragma unroll
        for (int n = 0; n < 4; ++n) acc[m][n] = (f32x4){0.f, 0.f, 0.f, 0.f};

    const int tr2 = tid >> 1;                  // staging row 0..127
    const int hh  = tid & 1;                   // 64-elem half
    const int wm  = tr2 & 7;                   // swizzle mask
    const short* gxa = Xb + (size_t)(bm + tr2) * DIM + hh * 64;
    const short* gwb = Wb + (size_t)(bn + tr2) * DIM + hh * 64;

    const int nkt = DIM / 128 / nks;
    const int kbase = ks * (DIM / nks);
    for (int kt = 0; kt < nkt; ++kt) {
        const int k0 = kbase + kt * 128;
        short8 ar[8], br[8];
#pragma unroll
        for (int q = 0; q < 8; ++q) ar[q] = *(const short8*)(gxa + k0 + q * 8);
#pragma unroll
        for (int q = 0; q < 8; ++q) br[q] = *(const short8*)(gwb + k0 + q * 8);
        __syncthreads();                       // previous tile's reads done
#pragma unroll
        for (int q = 0; q < 8; ++q) {
            const int sl = (hh * 8 + q) ^ wm;  // XOR-swizzled 16B slot
            *(short8*)&As[tr2 * 128 + sl * 8] = ar[q];
            *(short8*)&Bs[tr2 * 128 + sl * 8] = br[q];
        }
        __syncthreads();
#pragma unroll
        for (int kk = 0; kk < 128; kk += 32) {
            const int sbase = (kk + ke) >> 3;
            short8 af[4], bf[4];
#pragma unroll
            for (int m = 0; m < 4; ++m) {
                const int R = wr + m * 16 + fr;
                af[m] = *(const short8*)&As[R * 128 + ((sbase ^ (R & 7)) << 3)];
            }
#pragma unroll
            for (int n = 0; n < 4; ++n) {
                const int R = wc + n * 16 + fr;
                bf[n] = *(const short8*)&Bs[R * 128 + ((sbase ^ (R & 7)) << 3)];
            }
#pragma unroll
            for (int m = 0; m < 4; ++m)
#pragma unroll
                for (int n = 0; n < 4; ++n)
                    acc[m][n] = __builtin_amdgcn_mfma_f32_16x16x32_bf16(
                        __builtin_bit_cast(bf16x8, af[m]),
                        __builtin_bit_cast(bf16x8, bf[n]),
                        acc[m][n], 0, 0, 0);
        }
    }
    float* dst = ks ? (parts + (size_t)(ks - 1) * ROWS * DIM) : out;
#pragma unroll
    for (int n = 0; n < 4; ++n) {
        const int col = bn + wc + n * 16 + fr;
        const float bv = ks ? 0.f : bias[col];
#pragma unroll
        for (int m = 0; m < 4; ++m) {
            const int rbase = bm + wr + m * 16 + (lane >> 4) * 4;
#pragma unroll
            for (int r = 0; r < 4; ++r)
                dst[(size_t)(rbase + r) * DIM + col] = acc[m][n][r] + bv;
        }
    }
}

// ---------------------------------------------------------------------------
// 2b) fallback GEMM: fp32 staging, BM=64 BN=128, full K, 256 thr
// ---------------------------------------------------------------------------
#define LDT 72
__global__ __launch_bounds__(256) void kgemm_small(const float* __restrict__ X, const float* __restrict__ W,
                                                   const float* __restrict__ bias, float* __restrict__ out) {
    __shared__ short As[64 * LDT];
    __shared__ short Bs[128 * LDT];
    const int tid  = threadIdx.x;
    const int bn   = (blockIdx.x & 31) * 128;
    const int bm   = (blockIdx.x >> 5) * 64;
    const int lane = tid & 63;
    const int wv   = tid >> 6;
    const int wr   = (wv >> 1) * 32;
    const int wc   = (wv & 1) * 64;
    const int fr   = lane & 15;
    const int ke   = (lane >> 4) * 8;

    f32x4 acc[2][4];
#pragma unroll
    for (int m = 0; m < 2; ++m)
#pragma unroll
        for (int n = 0; n < 4; ++n) acc[m][n] = (f32x4){0.f, 0.f, 0.f, 0.f};

    const int tr = tid >> 2;
    const int tc = (tid & 3) << 4;

    for (int kt = 0; kt < DIM / 64; ++kt) {
        const int k0 = kt * 64;
        float4 ra[4], rb[2][4];
        {
            const float4* ga = (const float4*)(X + (size_t)(bm + tr) * DIM + k0 + tc);
#pragma unroll
            for (int q = 0; q < 4; ++q) ra[q] = ga[q];
#pragma unroll
            for (int h = 0; h < 2; ++h) {
                const float4* gw = (const float4*)(W + (size_t)(bn + h * 64 + tr) * DIM + k0 + tc);
#pragma unroll
                for (int q = 0; q < 4; ++q) rb[h][q] = gw[q];
            }
        }
        __syncthreads();
        *(short8*)&As[tr * LDT + tc]     = pack8(ra[0], ra[1]);
        *(short8*)&As[tr * LDT + tc + 8] = pack8(ra[2], ra[3]);
#pragma unroll
        for (int h = 0; h < 2; ++h) {
            *(short8*)&Bs[(h * 64 + tr) * LDT + tc]     = pack8(rb[h][0], rb[h][1]);
            *(short8*)&Bs[(h * 64 + tr) * LDT + tc + 8] = pack8(rb[h][2], rb[h][3]);
        }
        __syncthreads();
#pragma unroll
        for (int kk = 0; kk < 64; kk += 32) {
            short8 af[2], bf[4];
#pragma unroll
            for (int m = 0; m < 2; ++m)
                af[m] = *(const short8*)&As[(wr + m * 16 + fr) * LDT + kk + ke];
#pragma unroll
            for (int n = 0; n < 4; ++n)
                bf[n] = *(const short8*)&Bs[(wc + n * 16 + fr) * LDT + kk + ke];
#pragma unroll
            for (int m = 0; m < 2; ++m)
#pragma unroll
                for (int n = 0; n < 4; ++n)
                    acc[m][n] = __builtin_amdgcn_mfma_f32_16x16x32_bf16(
                        __builtin_bit_cast(bf16x8, af[m]),
                        __builtin_bit_cast(bf16x8, bf[n]),
                        acc[m][n], 0, 0, 0);
        }
    }
#pragma unroll
    for (int n = 0; n < 4; ++n) {
        const int col = bn + wc + n * 16 + fr;
        const float bv = bias[col];
#pragma unroll
        for (int m = 0; m < 2; ++m) {
            const int rbase = bm + wr + m * 16 + (lane >> 4) * 4;
#pragma unroll
            for (int r = 0; r < 4; ++r)
                out[(size_t)(rbase + r) * DIM + col] = acc[m][n][r] + bv;
        }
    }
}

// ---------------------------------------------------------------------------
// 3) walk kernel: 128 thr/block, 1 private row per wave, PAIR pipeline
// ---------------------------------------------------------------------------
__global__ __launch_bounds__(128) void kwalk(const float* __restrict__ X, const float* __restrict__ vec,
                                             const uint4* __restrict__ recs, const int* __restrict__ cnts,
                                             const float* __restrict__ parts, int nparts,
                                             float* __restrict__ out) {
    __shared__ float rowbuf[2][DIM + 8];
    const int wv   = threadIdx.x >> 6;
    const int lane = threadIdx.x & 63;
    float* rw = rowbuf[wv];
    const int row = blockIdx.x * 2 + wv;

    {   // init own row; pad slots 4096..4103 for identity records
        const float4* xr = (const float4*)(X + (size_t)row * DIM);
        float4* r4 = (float4*)rw;
        for (int c = lane; c < DIM / 4; c += 64) r4[c] = xr[c];
        if (lane < 8) rw[DIM + lane] = 0.f;
    }

    const int cnreg = cnts[lane < NSLOT ? lane : 0];

    for (int slot = 0; slot < NSLOT; ++slot) {
        if (slot == NW2) {      // between walks: yp = vec * yp (own row only)
            const float4* v4 = (const float4*)vec;
            float4* r4 = (float4*)rw;
            for (int c = lane; c < DIM / 4; c += 64) {
                float4 tv = r4[c]; const float4 v = v4[c];
                tv.x *= v.x; tv.y *= v.y; tv.z *= v.z; tv.w *= v.w;
                r4[c] = tv;
            }
        }
        const int nitp = (__shfl(cnreg, slot) >> 7) >> 1;   // pair count (>=4)
        const uint4* base = recs + (size_t)slot * SLOT;

        // ---- prologue: raw records pairs 0..3; decode+gather pair 0 -------
        uint4 R1[4], R2[4], R3[4], P0r[4];
#pragma unroll
        for (int r = 0; r < 4; ++r) {
            P0r[r] = base[(size_t)(0 * 256) + (r >> 1) * 128 + (r & 1) * 64 + lane];
            R1[r]  = base[(size_t)(1 * 256) + (r >> 1) * 128 + (r & 1) * 64 + lane];
            R2[r]  = base[(size_t)(2 * 256) + (r >> 1) * 128 + (r & 1) * 64 + lane];
            R3[r]  = base[(size_t)(3 * 256) + (r >> 1) * 128 + (r & 1) * 64 + lane];
        }
        int   pi[4], pj[4];
        float pc[4], ps[4], pgi[4], pgj[4];
#pragma unroll
        for (int r = 0; r < 4; ++r) {
            pi[r] = (int)P0r[r].x; pj[r] = (int)P0r[r].w;
            pc[r] = bitf(P0r[r].y); ps[r] = bitf(P0r[r].z);
        }
#pragma unroll
        for (int r = 0; r < 4; ++r) { pgi[r] = ldf(rw, pi[r]); pgj[r] = ldf(rw, pj[r]); }

#pragma unroll 2
        for (int p = 0; p < nitp; ++p) {
            // stage L: raw records for pair p+4 (clamped -> trailing pads)
            const int kc = (p + 4 < nitp) ? (p + 4) : (nitp - 1);
            const uint4* pb = base + (size_t)kc * 256;
            uint4 L[4];
#pragma unroll
            for (int r = 0; r < 4; ++r)
                L[r] = pb[(r >> 1) * 128 + (r & 1) * 64 + lane];

            // stage G: decode + gather pair p+1 (before pair-p scatters;
            // safe: any 4 consecutive chunks column-disjoint, pads idempotent)
            int   ti[4], tj[4];
            float tc[4], ts[4], tgi[4], tgj[4];
#pragma unroll
            for (int r = 0; r < 4; ++r) {
                ti[r] = (int)R1[r].x; tj[r] = (int)R1[r].w;
                tc[r] = bitf(R1[r].y); ts[r] = bitf(R1[r].z);
            }
#pragma unroll
            for (int r = 0; r < 4; ++r) { tgi[r] = ldf(rw, ti[r]); tgj[r] = ldf(rw, tj[r]); }

            // stage C: rotate + scatter pair p (4 records/lane, 1 row)
#pragma unroll
            for (int r = 0; r < 4; ++r) {
                const float wi = fmaf(pc[r], pgi[r],  ps[r] * pgj[r]);
                const float wj = fmaf(pc[r], pgj[r], -ps[r] * pgi[r]);
                stf(rw, pi[r], wi); stf(rw, pj[r], wj);
            }
            // rotate pipeline
#pragma unroll
            for (int r = 0; r < 4; ++r) {
                pi[r] = ti[r]; pj[r] = tj[r]; pc[r] = tc[r]; ps[r] = ts[r];
                pgi[r] = tgi[r]; pgj[r] = tgj[r];
                R1[r] = R2[r]; R2[r] = R3[r]; R3[r] = L[r];
            }
        }
    }

    // epilogue: out[row] += walked row + split-K partials
    float4* o4 = (float4*)(out + (size_t)row * DIM);
    const float4* r4 = (const float4*)rw;
    const size_t PS = (size_t)ROWS * DIM / 4;
    const float4* q = (const float4*)parts + (size_t)row * (DIM / 4);
    for (int c = lane; c < DIM / 4; c += 64) {
        float4 t = o4[c];
        const float4 s = r4[c];
        t.x += s.x; t.y += s.y; t.z += s.z; t.w += s.w;
        for (int p = 0; p < nparts; ++p) {
            const float4 a = q[c + (size_t)p * PS];
            t.x += a.x; t.y += a.y; t.z += a.z; t.w += a.w;
        }
        o4[c] = t;
    }
}

// ---------------------------------------------------------------------------
extern "C" void kernel_launch(void* const* d_in, const int* in_sizes, int n_in,
                              void* d_out, int out_size, void* d_ws, size_t ws_size,
                              hipStream_t stream) {
    const float* X    = (const float*)d_in[0];
    const float* W    = (const float*)d_in[1];
    const float* bias = (const float*)d_in[2];
    const float* vec  = (const float*)d_in[3];
    const int*   i1   = (const int*)d_in[4];
    const int*   j1   = (const int*)d_in[5];
    const float* c1   = (const float*)d_in[6];
    const float* s1   = (const float*)d_in[7];
    const int*   i2   = (const int*)d_in[8];
    const int*   j2   = (const int*)d_in[9];
    const float* c2   = (const float*)d_in[10];
    const float* s2   = (const float*)d_in[11];
    float* out = (float*)d_out;

    const size_t RD         = (size_t)ROWS * DIM * 4;            // 8 MiB
    const size_t WBB        = (size_t)DIM * DIM * 2;             // 32 MiB
    const size_t XBB        = (size_t)ROWS * DIM * 2;            // 4 MiB
    const size_t recs_bytes = (size_t)NSLOT * SLOT * 16;         // 6.29 MiB
    const size_t off_parts  = recs_bytes + 4096;

    // tiered Ksplit by workspace size
    int nks = 0;
    size_t off_wb = 0;
    {
        const size_t need4 = off_parts + 3 * RD + WBB + XBB;
        const size_t need2 = off_parts + 1 * RD + WBB + XBB;
        if      (ws_size >= need4) { nks = 4; off_wb = off_parts + 3 * RD; }
        else if (ws_size >= need2) { nks = 2; off_wb = off_parts + 1 * RD; }
    }

    uint4* recs  = (uint4*)d_ws;
    int*   cnts  = (int*)((char*)d_ws + recs_bytes);
    float* parts = (float*)((char*)d_ws + off_parts);
    short* wbuf  = (short*)((char*)d_ws + off_wb);
    short* xbuf  = (short*)((char*)d_ws + off_wb + WBB);
    const bool bf = (nks > 0);

    hipLaunchKernelGGL(kfused, dim3(NSLOT + (bf ? (NCVW + NCVX) : 0)), dim3(KT), 0, stream,
                       i1, j1, c1, s1, i2, j2, c2, s2, recs, cnts,
                       bf ? 1 : 0, W, X, wbuf, xbuf);
    if (bf)
        hipLaunchKernelGGL(kgemm_bf, dim3(128 * nks), dim3(256), 0, stream,
                           xbuf, wbuf, bias, out, parts, nks);
    else
        hipLaunchKernelGGL(kgemm_small, dim3(256), dim3(256), 0, stream, X, W, bias, out);
    hipLaunchKernelGGL(kwalk, dim3(ROWS / 2), dim3(128), 0, stream,
                       X, vec, recs, cnts, parts, bf ? (nks - 1) : 0, out);
}

// Round 13
// 296.793 us; speedup vs baseline: 1.1350x; 1.1350x over previous
//
#include <hip/hip_runtime.h>

// KacLayer: out[512][4096] = x @ W^T + b  +  Kac2( vec * Kac1( x ) )
//
//  kfused: blocks 0..11: per-8192-step window scheduler (R10 structure).
//          Election assigns dependency depth; one-shot level layout with +2
//          gap chunks between non-empty levels => column-sharing steps >=3
//          chunks apart => any 3 consecutive chunks column-disjoint.
//          Records scattered to global (pad-prefilled). Bit-exact reorder.
//          blocks 12..1163: fp32->bf16 convert of W and X into d_ws.
//  kgemm_bf: bf16 MFMA GEMM, 128x128 tile, BK=128, XOR-swizzled LDS,
//          runtime Ksplit (4 if ws allows, else 2) -> out + (nks-1) partials.
//  kwalk : 64 thr/block, 1 wave / 2 rows (float2-interleaved LDS).
//          3-stage pipeline with DEEP record ring: raw records for chunks
//          k+2..k+5 in registers, chunk k+6's loads in flight (~4 iters
//          (~800cy) load->decode slack, covering L3/far-L2 latency);
//          decode+gather chunk k+2 before chunk-k scatters (safe: any 3
//          consecutive chunks disjoint; in-order per-wave DS pipe).

#define DIM    4096
#define ROWS   512
#define NSTEPS 49152
#define WSTEPS 8192
#define NW2    (NSTEPS / WSTEPS)   // 6 windows per walk
#define NSLOT  (2 * NW2)           // 12 slots
#define MAXCHP 256
#define NSG    16                  // rank subgroups (one per wave)
#define CHUNK  128
#define SLOT   (MAXCHP * CHUNK)    // 32768 records per slot
#define MAXR   96
#define PADI   4096
#define PADJ   4097
#define KT     1024                // scheduler threads
#define SPT    (WSTEPS / KT)       // 8 steps per thread
#define NCVW   1024                // W-convert blocks
#define NCVX   128                 // X-convert blocks

typedef short  short8 __attribute__((ext_vector_type(8)));
typedef __bf16 bf16x8 __attribute__((ext_vector_type(8)));
typedef float  f32x4  __attribute__((ext_vector_type(4)));

__device__ inline short f2bf(float f) {
    unsigned u = __builtin_bit_cast(unsigned, f);
    u += 0x7FFFu + ((u >> 16) & 1u);
    return (short)(u >> 16);
}
__device__ inline short8 pack8(float4 a, float4 b) {
    short8 r;
    r[0] = f2bf(a.x); r[1] = f2bf(a.y); r[2] = f2bf(a.z); r[3] = f2bf(a.w);
    r[4] = f2bf(b.x); r[5] = f2bf(b.y); r[6] = f2bf(b.z); r[7] = f2bf(b.w);
    return r;
}
__device__ inline float bitf(unsigned u) { return __builtin_bit_cast(float, u); }
__device__ inline float2 ldrw(const float2* rw, int boff) {
    return *(const float2*)((const char*)rw + boff);
}
__device__ inline void strw(float2* rw, int boff, float2 v) {
    *(float2*)((char*)rw + boff) = v;
}

// ---------------------------------------------------------------------------
// 1) fused scheduler (blocks 0..NSLOT-1) + bf16 convert (blocks NSLOT..)
// ---------------------------------------------------------------------------
__global__ __launch_bounds__(KT) void kfused(
    const int* __restrict__ i1, const int* __restrict__ j1,
    const float* __restrict__ c1, const float* __restrict__ s1,
    const int* __restrict__ i2, const int* __restrict__ j2,
    const float* __restrict__ c2, const float* __restrict__ s2,
    uint4* __restrict__ recs, int* __restrict__ cnts,
    int doconv, const float* __restrict__ W, const float* __restrict__ X,
    short* __restrict__ wb, short* __restrict__ xb) {

    // ---------------- convert path ----------------
    if (blockIdx.x >= NSLOT) {
        if (!doconv) return;
        const int cb = blockIdx.x - NSLOT;
        const float* src; short* dst; size_t base;
        if (cb < NCVW) { src = W; dst = wb; base = (size_t)cb * 16384; }
        else           { src = X; dst = xb; base = (size_t)(cb - NCVW) * 16384; }
        const size_t o = base + (size_t)threadIdx.x * 16;
        const float4* s4 = (const float4*)(src + o);
        const float4 a0 = s4[0], a1 = s4[1], a2 = s4[2], a3 = s4[3];
        *(short8*)(dst + o)     = pack8(a0, a1);
        *(short8*)(dst + o + 8) = pack8(a2, a3);
        return;
    }

    // ---------------- scheduler path ----------------
    __shared__ unsigned tbl[DIM];          // election keys      (16 KB)
    __shared__ unsigned spair[WSTEPS];     // li | lj<<16        (32 KB)
    __shared__ unsigned lvrk[WSTEPS];      // rank<<8 | level    (32 KB)
    __shared__ int lcnt[MAXR * NSG];       // per-(level,wave) counters (6 KB)
    __shared__ int ltot[MAXR], chbase[MAXR];
    __shared__ int nchunks;

    const int b    = blockIdx.x;           // 0..11
    const int walk = b / NW2;
    const int w    = b % NW2;
    const int t    = threadIdx.x;
    const int gb   = w * WSTEPS;
    const int sg   = t >> 6;               // wave id 0..15

    const int*   I = walk ? i2 : i1;
    const int*   J = walk ? j2 : j1;
    const float* C = walk ? c2 : c1;
    const float* S = walk ? s2 : s1;

    uint4* slotp = recs + (size_t)b * SLOT;

    // prefill slot region with identity-pad records (coalesced)
    {
        const uint4 padrec = { (unsigned)(PADI * 8), 0x3F800000u, 0u, (unsigned)(PADJ * 8) };
        for (int k = t; k < SLOT; k += KT) slotp[k] = padrec;
    }
    for (int s = t; s < WSTEPS; s += KT)
        spair[s] = (unsigned)I[gb + s] | ((unsigned)J[gb + s] << 16);
    for (int k = t; k < DIM; k += KT) tbl[k] = 0xFFFFFFFFu;
    for (int k = t; k < MAXR * NSG; k += KT) lcnt[k] = 0;
    __syncthreads();

    // ---- election: 2 barriers/round; level = DAG depth --------------------
    unsigned pmask = (1u << SPT) - 1u;
    for (int rr = 0; rr < MAXR; ++rr) {
        const unsigned rk = (unsigned)(MAXR - 1 - rr) << 13;
#pragma unroll
        for (int q = 0; q < SPT; ++q)
            if (pmask & (1u << q)) {
                const int s = q * KT + t;
                const unsigned sp = spair[s];
                const unsigned key = rk | (unsigned)s;
                atomicMin(&tbl[sp & 0xFFFFu], key);
                atomicMin(&tbl[sp >> 16], key);
            }
        __syncthreads();                                   // B1
#pragma unroll
        for (int q = 0; q < SPT; ++q)
            if (pmask & (1u << q)) {
                const int s = q * KT + t;
                const unsigned sp = spair[s];
                const unsigned key = rk | (unsigned)s;
                if (tbl[sp & 0xFFFFu] == key && tbl[sp >> 16] == key) {
                    const int rank = atomicAdd(&lcnt[rr * NSG + sg], 1);
                    lvrk[s] = ((unsigned)rank << 8) | (unsigned)rr;
                    pmask &= ~(1u << q);
                }
            }
        const int np = __syncthreads_count(pmask != 0);    // B2
        if (np == 0) break;
    }
    // safety net (statistically unreachable)
#pragma unroll
    for (int q = 0; q < SPT; ++q)
        if (pmask & (1u << q)) {
            const int s = q * KT + t;
            const int rank = atomicAdd(&lcnt[(MAXR - 1) * NSG + sg], 1);
            lvrk[s] = ((unsigned)rank << 8) | (unsigned)(MAXR - 1);
        }
    __syncthreads();

    // ---- one-shot layout: level r -> ceil(cnt/128) chunks + 2 gap chunks --
    if (t < MAXR) {
        int run = 0;
        for (int g = 0; g < NSG; ++g) {
            const int v = lcnt[t * NSG + g];
            lcnt[t * NSG + g] = run;
            run += v;
        }
        ltot[t] = run;
    }
    __syncthreads();
    if (t < 64) {
        const int l = t;
        const int tot1 = ltot[l];
        const int w1 = (tot1 > 0) ? (((tot1 + 127) >> 7) + 2) : 0;
        int x1 = w1;
        for (int off = 1; off < 64; off <<= 1) {
            const int v = __shfl_up(x1, off);
            if (l >= off) x1 += v;
        }
        chbase[l] = x1 - w1;
        const int seg1 = __shfl(x1, 63);
        const int l2 = 64 + (l & 31);
        const int tot2 = ltot[l2];
        const int w2 = (tot2 > 0) ? (((tot2 + 127) >> 7) + 2) : 0;
        int x2 = w2;
        for (int off = 1; off < 32; off <<= 1) {
            const int v = __shfl_up(x2, off);
            if ((l & 31) >= off) x2 += v;
        }
        if (l < 32) chbase[l2] = seg1 + x2 - w2;
        if (l == 31) nchunks = seg1 + x2;
    }
    __syncthreads();
    if (t == 0) {
        int nc = nchunks;
        if (nc < 8) nc = 8;                 // deep-ring prologue needs >=6
        if (nc > MAXCHP) nc = MAXCHP;
        cnts[b] = nc * CHUNK;
    }

    // ---- record emission (float2 byte offsets = idx*8) --------------------
#pragma unroll
    for (int q = 0; q < SPT; ++q) {
        const int s = q * KT + t;
        const unsigned v = lvrk[s];
        const int lvl  = (int)(v & 0xFFu);
        const int rank = (int)(v >> 8) + lcnt[lvl * NSG + sg];
        const int p    = (chbase[lvl] + (rank >> 7)) * CHUNK + (rank & 127);
        if (p < SLOT) {
            const unsigned sp = spair[s];
            const int g = gb + s;
            uint4 r;
            r.x = (sp & 0xFFFFu) * 8u;
            r.y = __builtin_bit_cast(unsigned, C[g]);
            r.z = __builtin_bit_cast(unsigned, S[g]);
            r.w = (sp >> 16) * 8u;
            slotp[p] = r;
        }
    }
}

// ---------------------------------------------------------------------------
// 2a) bf16 GEMM: 128x128 tile, BK=128, runtime Ksplit nks
// ---------------------------------------------------------------------------
__global__ __launch_bounds__(256) void kgemm_bf(const short* __restrict__ Xb, const short* __restrict__ Wb,
                                                const float* __restrict__ bias, float* __restrict__ out,
                                                float* __restrict__ parts, int nks) {
    __shared__ short As[128 * 128];
    __shared__ short Bs[128 * 128];
    const int bid  = blockIdx.x;
    const int ks   = bid % nks;
    const int tile = bid / nks;                // 0..127
    const int bm   = (tile >> 5) * 128;
    const int bn   = (tile & 31) * 128;
    const int tid  = threadIdx.x;
    const int lane = tid & 63;
    const int wv   = tid >> 6;
    const int wr   = (wv >> 1) * 64;
    const int wc   = (wv & 1) * 64;
    const int fr   = lane & 15;
    const int ke   = (lane >> 4) * 8;

    f32x4 acc[4][4];
#pragma unroll
    for (int m = 0; m < 4; ++m)
#pragma unroll
        for (int n = 0; n < 4; ++n) acc[m][n] = (f32x4){0.f, 0.f, 0.f, 0.f};

    const int tr2 = tid >> 1;                  // staging row 0..127
    const int hh  = tid & 1;                   // 64-elem half
    const int wm  = tr2 & 7;                   // swizzle mask
    const short* gxa = Xb + (size_t)(bm + tr2) * DIM + hh * 64;
    const short* gwb = Wb + (size_t)(bn + tr2) * DIM + hh * 64;

    const int nkt = DIM / 128 / nks;
    const int kbase = ks * (DIM / nks);
    for (int kt = 0; kt < nkt; ++kt) {
        const int k0 = kbase + kt * 128;
        short8 ar[8], br[8];
#pragma unroll
        for (int q = 0; q < 8; ++q) ar[q] = *(const short8*)(gxa + k0 + q * 8);
#pragma unroll
        for (int q = 0; q < 8; ++q) br[q] = *(const short8*)(gwb + k0 + q * 8);
        __syncthreads();                       // previous tile's reads done
#pragma unroll
        for (int q = 0; q < 8; ++q) {
            const int sl = (hh * 8 + q) ^ wm;  // XOR-swizzled 16B slot
            *(short8*)&As[tr2 * 128 + sl * 8] = ar[q];
            *(short8*)&Bs[tr2 * 128 + sl * 8] = br[q];
        }
        __syncthreads();
#pragma unroll
        for (int kk = 0; kk < 128; kk += 32) {
            const int sbase = (kk + ke) >> 3;
            short8 af[4], bf[4];
#pragma unroll
            for (int m = 0; m < 4; ++m) {
                const int R = wr + m * 16 + fr;
                af[m] = *(const short8*)&As[R * 128 + ((sbase ^ (R & 7)) << 3)];
            }
#pragma unroll
            for (int n = 0; n < 4; ++n) {
                const int R = wc + n * 16 + fr;
                bf[n] = *(const short8*)&Bs[R * 128 + ((sbase ^ (R & 7)) << 3)];
            }
#pragma unroll
            for (int m = 0; m < 4; ++m)
#pragma unroll
                for (int n = 0; n < 4; ++n)
                    acc[m][n] = __builtin_amdgcn_mfma_f32_16x16x32_bf16(
                        __builtin_bit_cast(bf16x8, af[m]),
                        __builtin_bit_cast(bf16x8, bf[n]),
                        acc[m][n], 0, 0, 0);
        }
    }
    float* dst = ks ? (parts + (size_t)(ks - 1) * ROWS * DIM) : out;
#pragma unroll
    for (int n = 0; n < 4; ++n) {
        const int col = bn + wc + n * 16 + fr;
        const float bv = ks ? 0.f : bias[col];
#pragma unroll
        for (int m = 0; m < 4; ++m) {
            const int rbase = bm + wr + m * 16 + (lane >> 4) * 4;
#pragma unroll
            for (int r = 0; r < 4; ++r)
                dst[(size_t)(rbase + r) * DIM + col] = acc[m][n][r] + bv;
        }
    }
}

// ---------------------------------------------------------------------------
// 2b) fallback GEMM: fp32 staging, BM=64 BN=128, full K, 256 thr
// ---------------------------------------------------------------------------
#define LDT 72
__global__ __launch_bounds__(256) void kgemm_small(const float* __restrict__ X, const float* __restrict__ W,
                                                   const float* __restrict__ bias, float* __restrict__ out) {
    __shared__ short As[64 * LDT];
    __shared__ short Bs[128 * LDT];
    const int tid  = threadIdx.x;
    const int bn   = (blockIdx.x & 31) * 128;
    const int bm   = (blockIdx.x >> 5) * 64;
    const int lane = tid & 63;
    const int wv   = tid >> 6;
    const int wr   = (wv >> 1) * 32;
    const int wc   = (wv & 1) * 64;
    const int fr   = lane & 15;
    const int ke   = (lane >> 4) * 8;

    f32x4 acc[2][4];
#pragma unroll
    for (int m = 0; m < 2; ++m)
#pragma unroll
        for (int n = 0; n < 4; ++n) acc[m][n] = (f32x4){0.f, 0.f, 0.f, 0.f};

    const int tr = tid >> 2;
    const int tc = (tid & 3) << 4;

    for (int kt = 0; kt < DIM / 64; ++kt) {
        const int k0 = kt * 64;
        float4 ra[4], rb[2][4];
        {
            const float4* ga = (const float4*)(X + (size_t)(bm + tr) * DIM + k0 + tc);
#pragma unroll
            for (int q = 0; q < 4; ++q) ra[q] = ga[q];
#pragma unroll
            for (int h = 0; h < 2; ++h) {
                const float4* gw = (const float4*)(W + (size_t)(bn + h * 64 + tr) * DIM + k0 + tc);
#pragma unroll
                for (int q = 0; q < 4; ++q) rb[h][q] = gw[q];
            }
        }
        __syncthreads();
        *(short8*)&As[tr * LDT + tc]     = pack8(ra[0], ra[1]);
        *(short8*)&As[tr * LDT + tc + 8] = pack8(ra[2], ra[3]);
#pragma unroll
        for (int h = 0; h < 2; ++h) {
            *(short8*)&Bs[(h * 64 + tr) * LDT + tc]     = pack8(rb[h][0], rb[h][1]);
            *(short8*)&Bs[(h * 64 + tr) * LDT + tc + 8] = pack8(rb[h][2], rb[h][3]);
        }
        __syncthreads();
#pragma unroll
        for (int kk = 0; kk < 64; kk += 32) {
            short8 af[2], bf[4];
#pragma unroll
            for (int m = 0; m < 2; ++m)
                af[m] = *(const short8*)&As[(wr + m * 16 + fr) * LDT + kk + ke];
#pragma unroll
            for (int n = 0; n < 4; ++n)
                bf[n] = *(const short8*)&Bs[(wc + n * 16 + fr) * LDT + kk + ke];
#pragma unroll
            for (int m = 0; m < 2; ++m)
#pragma unroll
                for (int n = 0; n < 4; ++n)
                    acc[m][n] = __builtin_amdgcn_mfma_f32_16x16x32_bf16(
                        __builtin_bit_cast(bf16x8, af[m]),
                        __builtin_bit_cast(bf16x8, bf[n]),
                        acc[m][n], 0, 0, 0);
        }
    }
#pragma unroll
    for (int n = 0; n < 4; ++n) {
        const int col = bn + wc + n * 16 + fr;
        const float bv = bias[col];
#pragma unroll
        for (int m = 0; m < 2; ++m) {
            const int rbase = bm + wr + m * 16 + (lane >> 4) * 4;
#pragma unroll
            for (int r = 0; r < 4; ++r)
                out[(size_t)(rbase + r) * DIM + col] = acc[m][n][r] + bv;
        }
    }
}

// ---------------------------------------------------------------------------
// 3) walk kernel: 1 wave / 2 rows, 3-stage pipeline with 4-deep record ring
// ---------------------------------------------------------------------------
__global__ __launch_bounds__(64) void kwalk(const float* __restrict__ X, const float* __restrict__ vec,
                                            const uint4* __restrict__ recs, const int* __restrict__ cnts,
                                            const float* __restrict__ parts, int nparts,
                                            float* __restrict__ out) {
    __shared__ float2 rw[DIM + 2];
    const int pr   = blockIdx.x;
    const int lane = threadIdx.x;
    const int rA   = pr * 2, rB = pr * 2 + 1;

    {
        const float4* xa = (const float4*)(X + (size_t)rA * DIM);
        const float4* xb = (const float4*)(X + (size_t)rB * DIM);
        for (int c4 = lane; c4 < DIM / 4; c4 += 64) {
            const float4 a = xa[c4], b = xb[c4];
            rw[c4 * 4 + 0] = make_float2(a.x, b.x);
            rw[c4 * 4 + 1] = make_float2(a.y, b.y);
            rw[c4 * 4 + 2] = make_float2(a.z, b.z);
            rw[c4 * 4 + 3] = make_float2(a.w, b.w);
        }
        if (lane < 2) rw[DIM + lane] = make_float2(0.f, 0.f);
    }

    const int cnreg = cnts[lane < NSLOT ? lane : 0];

    for (int slot = 0; slot < NSLOT; ++slot) {
        if (slot == NW2) {      // between walks: yp = vec * yp
            const float4* v4 = (const float4*)vec;
            for (int c4 = lane; c4 < DIM / 4; c4 += 64) {
                const float4 v = v4[c4];
#pragma unroll
                for (int q = 0; q < 4; ++q) {
                    float2 tv = rw[c4 * 4 + q];
                    const float sc = (q == 0) ? v.x : (q == 1) ? v.y : (q == 2) ? v.z : v.w;
                    tv.x *= sc; tv.y *= sc;
                    rw[c4 * 4 + q] = tv;
                }
            }
        }
        const int nit = __shfl(cnreg, slot) >> 7;      // chunks (>=8)
        const uint4* base = recs + (size_t)slot * SLOT;

        // ---- prologue: ring holds raw chunks k+2..k+5 (k=0); decode 0,1 ---
        uint4 rg0A = base[2 * 128 + lane], rg0B = base[2 * 128 + 64 + lane];
        uint4 rg1A = base[3 * 128 + lane], rg1B = base[3 * 128 + 64 + lane];
        uint4 rg2A = base[4 * 128 + lane], rg2B = base[4 * 128 + 64 + lane];
        uint4 rg3A = base[5 * 128 + lane], rg3B = base[5 * 128 + 64 + lane];
        const uint4 c0A = base[lane],       c0B = base[64 + lane];
        const uint4 c1A = base[128 + lane], c1B = base[192 + lane];

        int   i0a = (int)c0A.x, j0a = (int)c0A.w;      // float2 byte offsets
        int   i0b = (int)c0B.x, j0b = (int)c0B.w;
        float cc0a = bitf(c0A.y), ss0a = bitf(c0A.z);
        float cc0b = bitf(c0B.y), ss0b = bitf(c0B.z);
        float2 g0ai = ldrw(rw, i0a), g0aj = ldrw(rw, j0a);
        float2 g0bi = ldrw(rw, i0b), g0bj = ldrw(rw, j0b);

        int   i1a = (int)c1A.x, j1a = (int)c1A.w;
        int   i1b = (int)c1B.x, j1b = (int)c1B.w;
        float cc1a = bitf(c1A.y), ss1a = bitf(c1A.z);
        float cc1b = bitf(c1B.y), ss1b = bitf(c1B.z);
        float2 g1ai = ldrw(rw, i1a), g1aj = ldrw(rw, j1a);
        float2 g1bi = ldrw(rw, i1b), g1bj = ldrw(rw, j1b);

#pragma unroll 4
        for (int k = 0; k < nit; ++k) {
            // stage L: load records for chunk k+6 (clamped -> trailing pads)
            const int kc = (k + 6 < nit) ? (k + 6) : (nit - 1);
            const uint4 mA = base[(size_t)kc * 128 + lane];
            const uint4 mB = base[(size_t)kc * 128 + 64 + lane];

            // stage G: decode + gather chunk k+2 (ring head; ~4 iters since
            // its load -> L3 latency covered; any 3 consecutive disjoint)
            const int   i2a = (int)rg0A.x, j2a = (int)rg0A.w;
            const int   i2b = (int)rg0B.x, j2b = (int)rg0B.w;
            const float cc2a = bitf(rg0A.y), ss2a = bitf(rg0A.z);
            const float cc2b = bitf(rg0B.y), ss2b = bitf(rg0B.z);
            const float2 g2ai = ldrw(rw, i2a), g2aj = ldrw(rw, j2a);
            const float2 g2bi = ldrw(rw, i2b), g2bj = ldrw(rw, j2b);

            // stage C: rotate + scatter chunk k
            float2 wia, wja, wib, wjb;
            wia.x = fmaf(cc0a, g0ai.x,  ss0a * g0aj.x);
            wia.y = fmaf(cc0a, g0ai.y,  ss0a * g0aj.y);
            wja.x = fmaf(cc0a, g0aj.x, -ss0a * g0ai.x);
            wja.y = fmaf(cc0a, g0aj.y, -ss0a * g0ai.y);
            wib.x = fmaf(cc0b, g0bi.x,  ss0b * g0bj.x);
            wib.y = fmaf(cc0b, g0bi.y,  ss0b * g0bj.y);
            wjb.x = fmaf(cc0b, g0bj.x, -ss0b * g0bi.x);
            wjb.y = fmaf(cc0b, g0bj.y, -ss0b * g0bi.y);
            strw(rw, i0a, wia); strw(rw, j0a, wja);
            strw(rw, i0b, wib); strw(rw, j0b, wjb);

            // rotate pipeline (unroll-4 renames the copies away)
            i0a = i1a; j0a = j1a; cc0a = cc1a; ss0a = ss1a; g0ai = g1ai; g0aj = g1aj;
            i0b = i1b; j0b = j1b; cc0b = cc1b; ss0b = ss1b; g0bi = g1bi; g0bj = g1bj;
            i1a = i2a; j1a = j2a; cc1a = cc2a; ss1a = ss2a; g1ai = g2ai; g1aj = g2aj;
            i1b = i2b; j1b = j2b; cc1b = cc2b; ss1b = ss2b; g1bi = g2bi; g1bj = g2bj;
            rg0A = rg1A; rg0B = rg1B;
            rg1A = rg2A; rg1B = rg2B;
            rg2A = rg3A; rg2B = rg3B;
            rg3A = mA;   rg3B = mB;
        }
    }

    float4* oa = (float4*)(out + (size_t)rA * DIM);
    float4* ob = (float4*)(out + (size_t)rB * DIM);
    const size_t PS = (size_t)ROWS * DIM / 4;
    const float4* qa = (const float4*)parts + (size_t)rA * (DIM / 4);
    const float4* qb = (const float4*)parts + (size_t)rB * (DIM / 4);
    for (int c4 = lane; c4 < DIM / 4; c4 += 64) {
        const float2 p0 = rw[c4 * 4 + 0], p1 = rw[c4 * 4 + 1];
        const float2 p2 = rw[c4 * 4 + 2], p3 = rw[c4 * 4 + 3];
        float4 ta = oa[c4], tb = ob[c4];
        for (int p = 0; p < nparts; ++p) {
            const float4 a = qa[c4 + (size_t)p * PS];
            const float4 b = qb[c4 + (size_t)p * PS];
            ta.x += a.x; ta.y += a.y; ta.z += a.z; ta.w += a.w;
            tb.x += b.x; tb.y += b.y; tb.z += b.z; tb.w += b.w;
        }
        ta.x += p0.x; ta.y += p1.x; ta.z += p2.x; ta.w += p3.x;
        tb.x += p0.y; tb.y += p1.y; tb.z += p2.y; tb.w += p3.y;
        oa[c4] = ta; ob[c4] = tb;
    }
}

// ---------------------------------------------------------------------------
extern "C" void kernel_launch(void* const* d_in, const int* in_sizes, int n_in,
                              void* d_out, int out_size, void* d_ws, size_t ws_size,
                              hipStream_t stream) {
    const float* X    = (const float*)d_in[0];
    const float* W    = (const float*)d_in[1];
    const float* bias = (const float*)d_in[2];
    const float* vec  = (const float*)d_in[3];
    const int*   i1   = (const int*)d_in[4];
    const int*   j1   = (const int*)d_in[5];
    const float* c1   = (const float*)d_in[6];
    const float* s1   = (const float*)d_in[7];
    const int*   i2   = (const int*)d_in[8];
    const int*   j2   = (const int*)d_in[9];
    const float* c2   = (const float*)d_in[10];
    const float* s2   = (const float*)d_in[11];
    float* out = (float*)d_out;

    const size_t RD         = (size_t)ROWS * DIM * 4;            // 8 MiB
    const size_t WBB        = (size_t)DIM * DIM * 2;             // 32 MiB
    const size_t XBB        = (size_t)ROWS * DIM * 2;            // 4 MiB
    const size_t recs_bytes = (size_t)NSLOT * SLOT * 16;         // 6.29 MiB
    const size_t off_parts  = recs_bytes + 4096;

    // tiered Ksplit by workspace size
    int nks = 0;
    size_t off_wb = 0;
    {
        const size_t need4 = off_parts + 3 * RD + WBB + XBB;
        const size_t need2 = off_parts + 1 * RD + WBB + XBB;
        if      (ws_size >= need4) { nks = 4; off_wb = off_parts + 3 * RD; }
        else if (ws_size >= need2) { nks = 2; off_wb = off_parts + 1 * RD; }
    }

    uint4* recs  = (uint4*)d_ws;
    int*   cnts  = (int*)((char*)d_ws + recs_bytes);
    float* parts = (float*)((char*)d_ws + off_parts);
    short* wbuf  = (short*)((char*)d_ws + off_wb);
    short* xbuf  = (short*)((char*)d_ws + off_wb + WBB);
    const bool bf = (nks > 0);

    hipLaunchKernelGGL(kfused, dim3(NSLOT + (bf ? (NCVW + NCVX) : 0)), dim3(KT), 0, stream,
                       i1, j1, c1, s1, i2, j2, c2, s2, recs, cnts,
                       bf ? 1 : 0, W, X, wbuf, xbuf);
    if (bf)
        hipLaunchKernelGGL(kgemm_bf, dim3(128 * nks), dim3(256), 0, stream,
                           xbuf, wbuf, bias, out, parts, nks);
    else
        hipLaunchKernelGGL(kgemm_small, dim3(256), dim3(256), 0, stream, X, W, bias, out);
    hipLaunchKernelGGL(kwalk, dim3(ROWS / 2), dim3(64), 0, stream,
                       X, vec, recs, cnts, parts, bf ? (nks - 1) : 0, out);
}

// Round 14
// 254.033 us; speedup vs baseline: 1.3261x; 1.1683x over previous
//
#include <hip/hip_runtime.h>

// KacLayer: out[512][4096] = x @ W^T + b  +  Kac2( vec * Kac1( x ) )
//
//  kfused: blocks 0..11: per-8192-step window scheduler. Election assigns
//          dependency depth (2 barriers/round); one-shot level layout with
//          NO gaps: level r -> ceil(cnt_r/128) chunks, levels back-to-back.
//          Dependent steps land in later chunks (depth order); adjacent-chunk
//          RAW through LDS is handled by the in-order per-wave DS pipe
//          (validated R1-R3). Records scattered to global (pad-prefilled:
//          ceil-waste slots are identity rotations on columns 4096/4097).
//          Bit-exact reorder of commuting Givens rotations.
//          blocks 12..1163: fp32->bf16 convert of W and X into d_ws.
//  kgemm_bf: bf16 MFMA GEMM, 128x128 tile, BK=128, XOR-swizzled LDS,
//          runtime Ksplit (4 if ws allows, else 2) -> out + (nks-1) partials.
//  kwalk : 64 thr/block, 1 wave / 2 rows (float2-interleaved LDS).
//          Per iteration: decode ring-head records (loaded 3 iters earlier,
//          L2/L3 latency hidden), gather 4x ds_read_b64, rotate, scatter
//          4x ds_write_b64. No gather-ahead: per-iter cost is one LDS
//          round-trip either way (R13 measurement), so we take the
//          gap-free packing (~950 chunks vs 1860) instead.

#define DIM    4096
#define ROWS   512
#define NSTEPS 49152
#define WSTEPS 8192
#define NW2    (NSTEPS / WSTEPS)   // 6 windows per walk
#define NSLOT  (2 * NW2)           // 12 slots
#define MAXCHP 256
#define NSG    16                  // rank subgroups (one per wave)
#define CHUNK  128
#define SLOT   (MAXCHP * CHUNK)    // 32768 records per slot
#define MAXR   96
#define PADI   4096
#define PADJ   4097
#define KT     1024                // scheduler threads
#define SPT    (WSTEPS / KT)       // 8 steps per thread
#define NCVW   1024                // W-convert blocks
#define NCVX   128                 // X-convert blocks

typedef short  short8 __attribute__((ext_vector_type(8)));
typedef __bf16 bf16x8 __attribute__((ext_vector_type(8)));
typedef float  f32x4  __attribute__((ext_vector_type(4)));

__device__ inline short f2bf(float f) {
    unsigned u = __builtin_bit_cast(unsigned, f);
    u += 0x7FFFu + ((u >> 16) & 1u);
    return (short)(u >> 16);
}
__device__ inline short8 pack8(float4 a, float4 b) {
    short8 r;
    r[0] = f2bf(a.x); r[1] = f2bf(a.y); r[2] = f2bf(a.z); r[3] = f2bf(a.w);
    r[4] = f2bf(b.x); r[5] = f2bf(b.y); r[6] = f2bf(b.z); r[7] = f2bf(b.w);
    return r;
}
__device__ inline float bitf(unsigned u) { return __builtin_bit_cast(float, u); }
__device__ inline float2 ldrw(const float2* rw, int boff) {
    return *(const float2*)((const char*)rw + boff);
}
__device__ inline void strw(float2* rw, int boff, float2 v) {
    *(float2*)((char*)rw + boff) = v;
}

// ---------------------------------------------------------------------------
// 1) fused scheduler (blocks 0..NSLOT-1) + bf16 convert (blocks NSLOT..)
// ---------------------------------------------------------------------------
__global__ __launch_bounds__(KT) void kfused(
    const int* __restrict__ i1, const int* __restrict__ j1,
    const float* __restrict__ c1, const float* __restrict__ s1,
    const int* __restrict__ i2, const int* __restrict__ j2,
    const float* __restrict__ c2, const float* __restrict__ s2,
    uint4* __restrict__ recs, int* __restrict__ cnts,
    int doconv, const float* __restrict__ W, const float* __restrict__ X,
    short* __restrict__ wb, short* __restrict__ xb) {

    // ---------------- convert path ----------------
    if (blockIdx.x >= NSLOT) {
        if (!doconv) return;
        const int cb = blockIdx.x - NSLOT;
        const float* src; short* dst; size_t base;
        if (cb < NCVW) { src = W; dst = wb; base = (size_t)cb * 16384; }
        else           { src = X; dst = xb; base = (size_t)(cb - NCVW) * 16384; }
        const size_t o = base + (size_t)threadIdx.x * 16;
        const float4* s4 = (const float4*)(src + o);
        const float4 a0 = s4[0], a1 = s4[1], a2 = s4[2], a3 = s4[3];
        *(short8*)(dst + o)     = pack8(a0, a1);
        *(short8*)(dst + o + 8) = pack8(a2, a3);
        return;
    }

    // ---------------- scheduler path ----------------
    __shared__ unsigned tbl[DIM];          // election keys      (16 KB)
    __shared__ unsigned spair[WSTEPS];     // li | lj<<16        (32 KB)
    __shared__ unsigned lvrk[WSTEPS];      // rank<<8 | level    (32 KB)
    __shared__ int lcnt[MAXR * NSG];       // per-(level,wave) counters (6 KB)
    __shared__ int ltot[MAXR], chbase[MAXR];
    __shared__ int nchunks;

    const int b    = blockIdx.x;           // 0..11
    const int walk = b / NW2;
    const int w    = b % NW2;
    const int t    = threadIdx.x;
    const int gb   = w * WSTEPS;
    const int sg   = t >> 6;               // wave id 0..15

    const int*   I = walk ? i2 : i1;
    const int*   J = walk ? j2 : j1;
    const float* C = walk ? c2 : c1;
    const float* S = walk ? s2 : s1;

    uint4* slotp = recs + (size_t)b * SLOT;

    // prefill slot region with identity-pad records (coalesced)
    {
        const uint4 padrec = { (unsigned)(PADI * 8), 0x3F800000u, 0u, (unsigned)(PADJ * 8) };
        for (int k = t; k < SLOT; k += KT) slotp[k] = padrec;
    }
    for (int s = t; s < WSTEPS; s += KT)
        spair[s] = (unsigned)I[gb + s] | ((unsigned)J[gb + s] << 16);
    for (int k = t; k < DIM; k += KT) tbl[k] = 0xFFFFFFFFu;
    for (int k = t; k < MAXR * NSG; k += KT) lcnt[k] = 0;
    __syncthreads();

    // ---- election: 2 barriers/round; level = DAG depth --------------------
    unsigned pmask = (1u << SPT) - 1u;
    for (int rr = 0; rr < MAXR; ++rr) {
        const unsigned rk = (unsigned)(MAXR - 1 - rr) << 13;
#pragma unroll
        for (int q = 0; q < SPT; ++q)
            if (pmask & (1u << q)) {
                const int s = q * KT + t;
                const unsigned sp = spair[s];
                const unsigned key = rk | (unsigned)s;
                atomicMin(&tbl[sp & 0xFFFFu], key);
                atomicMin(&tbl[sp >> 16], key);
            }
        __syncthreads();                                   // B1
#pragma unroll
        for (int q = 0; q < SPT; ++q)
            if (pmask & (1u << q)) {
                const int s = q * KT + t;
                const unsigned sp = spair[s];
                const unsigned key = rk | (unsigned)s;
                if (tbl[sp & 0xFFFFu] == key && tbl[sp >> 16] == key) {
                    const int rank = atomicAdd(&lcnt[rr * NSG + sg], 1);
                    lvrk[s] = ((unsigned)rank << 8) | (unsigned)rr;
                    pmask &= ~(1u << q);
                }
            }
        const int np = __syncthreads_count(pmask != 0);    // B2
        if (np == 0) break;
    }
    // safety net (statistically unreachable)
#pragma unroll
    for (int q = 0; q < SPT; ++q)
        if (pmask & (1u << q)) {
            const int s = q * KT + t;
            const int rank = atomicAdd(&lcnt[(MAXR - 1) * NSG + sg], 1);
            lvrk[s] = ((unsigned)rank << 8) | (unsigned)(MAXR - 1);
        }
    __syncthreads();

    // ---- one-shot layout: level r -> ceil(cnt/128) chunks, NO gaps --------
    if (t < MAXR) {
        int run = 0;
        for (int g = 0; g < NSG; ++g) {
            const int v = lcnt[t * NSG + g];
            lcnt[t * NSG + g] = run;
            run += v;
        }
        ltot[t] = run;
    }
    __syncthreads();
    if (t < 64) {
        const int l = t;
        const int tot1 = ltot[l];
        const int w1 = (tot1 + 127) >> 7;
        int x1 = w1;
        for (int off = 1; off < 64; off <<= 1) {
            const int v = __shfl_up(x1, off);
            if (l >= off) x1 += v;
        }
        chbase[l] = x1 - w1;
        const int seg1 = __shfl(x1, 63);
        const int l2 = 64 + (l & 31);
        const int tot2 = ltot[l2];
        const int w2 = (tot2 + 127) >> 7;
        int x2 = w2;
        for (int off = 1; off < 32; off <<= 1) {
            const int v = __shfl_up(x2, off);
            if ((l & 31) >= off) x2 += v;
        }
        if (l < 32) chbase[l2] = seg1 + x2 - w2;
        if (l == 31) nchunks = seg1 + x2;
    }
    __syncthreads();
    if (t == 0) {
        int nc = nchunks;
        if (nc < 4) nc = 4;                 // ring-3 prologue needs >=4
        if (nc > MAXCHP) nc = MAXCHP;
        cnts[b] = nc * CHUNK;
    }

    // ---- record emission (float2 byte offsets = idx*8) --------------------
#pragma unroll
    for (int q = 0; q < SPT; ++q) {
        const int s = q * KT + t;
        const unsigned v = lvrk[s];
        const int lvl  = (int)(v & 0xFFu);
        const int rank = (int)(v >> 8) + lcnt[lvl * NSG + sg];
        const int p    = (chbase[lvl] + (rank >> 7)) * CHUNK + (rank & 127);
        if (p < SLOT) {
            const unsigned sp = spair[s];
            const int g = gb + s;
            uint4 r;
            r.x = (sp & 0xFFFFu) * 8u;
            r.y = __builtin_bit_cast(unsigned, C[g]);
            r.z = __builtin_bit_cast(unsigned, S[g]);
            r.w = (sp >> 16) * 8u;
            slotp[p] = r;
        }
    }
}

// ---------------------------------------------------------------------------
// 2a) bf16 GEMM: 128x128 tile, BK=128, runtime Ksplit nks
// ---------------------------------------------------------------------------
__global__ __launch_bounds__(256) void kgemm_bf(const short* __restrict__ Xb, const short* __restrict__ Wb,
                                                const float* __restrict__ bias, float* __restrict__ out,
                                                float* __restrict__ parts, int nks) {
    __shared__ short As[128 * 128];
    __shared__ short Bs[128 * 128];
    const int bid  = blockIdx.x;
    const int ks   = bid % nks;
    const int tile = bid / nks;                // 0..127
    const int bm   = (tile >> 5) * 128;
    const int bn   = (tile & 31) * 128;
    const int tid  = threadIdx.x;
    const int lane = tid & 63;
    const int wv   = tid >> 6;
    const int wr   = (wv >> 1) * 64;
    const int wc   = (wv & 1) * 64;
    const int fr   = lane & 15;
    const int ke   = (lane >> 4) * 8;

    f32x4 acc[4][4];
#pragma unroll
    for (int m = 0; m < 4; ++m)
#pragma unroll
        for (int n = 0; n < 4; ++n) acc[m][n] = (f32x4){0.f, 0.f, 0.f, 0.f};

    const int tr2 = tid >> 1;                  // staging row 0..127
    const int hh  = tid & 1;                   // 64-elem half
    const int wm  = tr2 & 7;                   // swizzle mask
    const short* gxa = Xb + (size_t)(bm + tr2) * DIM + hh * 64;
    const short* gwb = Wb + (size_t)(bn + tr2) * DIM + hh * 64;

    const int nkt = DIM / 128 / nks;
    const int kbase = ks * (DIM / nks);
    for (int kt = 0; kt < nkt; ++kt) {
        const int k0 = kbase + kt * 128;
        short8 ar[8], br[8];
#pragma unroll
        for (int q = 0; q < 8; ++q) ar[q] = *(const short8*)(gxa + k0 + q * 8);
#pragma unroll
        for (int q = 0; q < 8; ++q) br[q] = *(const short8*)(gwb + k0 + q * 8);
        __syncthreads();                       // previous tile's reads done
#pragma unroll
        for (int q = 0; q < 8; ++q) {
            const int sl = (hh * 8 + q) ^ wm;  // XOR-swizzled 16B slot
            *(short8*)&As[tr2 * 128 + sl * 8] = ar[q];
            *(short8*)&Bs[tr2 * 128 + sl * 8] = br[q];
        }
        __syncthreads();
#pragma unroll
        for (int kk = 0; kk < 128; kk += 32) {
            const int sbase = (kk + ke) >> 3;
            short8 af[4], bf[4];
#pragma unroll
            for (int m = 0; m < 4; ++m) {
                const int R = wr + m * 16 + fr;
                af[m] = *(const short8*)&As[R * 128 + ((sbase ^ (R & 7)) << 3)];
            }
#pragma unroll
            for (int n = 0; n < 4; ++n) {
                const int R = wc + n * 16 + fr;
                bf[n] = *(const short8*)&Bs[R * 128 + ((sbase ^ (R & 7)) << 3)];
            }
#pragma unroll
            for (int m = 0; m < 4; ++m)
#pragma unroll
                for (int n = 0; n < 4; ++n)
                    acc[m][n] = __builtin_amdgcn_mfma_f32_16x16x32_bf16(
                        __builtin_bit_cast(bf16x8, af[m]),
                        __builtin_bit_cast(bf16x8, bf[n]),
                        acc[m][n], 0, 0, 0);
        }
    }
    float* dst = ks ? (parts + (size_t)(ks - 1) * ROWS * DIM) : out;
#pragma unroll
    for (int n = 0; n < 4; ++n) {
        const int col = bn + wc + n * 16 + fr;
        const float bv = ks ? 0.f : bias[col];
#pragma unroll
        for (int m = 0; m < 4; ++m) {
            const int rbase = bm + wr + m * 16 + (lane >> 4) * 4;
#pragma unroll
            for (int r = 0; r < 4; ++r)
                dst[(size_t)(rbase + r) * DIM + col] = acc[m][n][r] + bv;
        }
    }
}

// ---------------------------------------------------------------------------
// 2b) fallback GEMM: fp32 staging, BM=64 BN=128, full K, 256 thr
// ---------------------------------------------------------------------------
#define LDT 72
__global__ __launch_bounds__(256) void kgemm_small(const float* __restrict__ X, const float* __restrict__ W,
                                                   const float* __restrict__ bias, float* __restrict__ out) {
    __shared__ short As[64 * LDT];
    __shared__ short Bs[128 * LDT];
    const int tid  = threadIdx.x;
    const int bn   = (blockIdx.x & 31) * 128;
    const int bm   = (blockIdx.x >> 5) * 64;
    const int lane = tid & 63;
    const int wv   = tid >> 6;
    const int wr   = (wv >> 1) * 32;
    const int wc   = (wv & 1) * 64;
    const int fr   = lane & 15;
    const int ke   = (lane >> 4) * 8;

    f32x4 acc[2][4];
#pragma unroll
    for (int m = 0; m < 2; ++m)
#pragma unroll
        for (int n = 0; n < 4; ++n) acc[m][n] = (f32x4){0.f, 0.f, 0.f, 0.f};

    const int tr = tid >> 2;
    const int tc = (tid & 3) << 4;

    for (int kt = 0; kt < DIM / 64; ++kt) {
        const int k0 = kt * 64;
        float4 ra[4], rb[2][4];
        {
            const float4* ga = (const float4*)(X + (size_t)(bm + tr) * DIM + k0 + tc);
#pragma unroll
            for (int q = 0; q < 4; ++q) ra[q] = ga[q];
#pragma unroll
            for (int h = 0; h < 2; ++h) {
                const float4* gw = (const float4*)(W + (size_t)(bn + h * 64 + tr) * DIM + k0 + tc);
#pragma unroll
                for (int q = 0; q < 4; ++q) rb[h][q] = gw[q];
            }
        }
        __syncthreads();
        *(short8*)&As[tr * LDT + tc]     = pack8(ra[0], ra[1]);
        *(short8*)&As[tr * LDT + tc + 8] = pack8(ra[2], ra[3]);
#pragma unroll
        for (int h = 0; h < 2; ++h) {
            *(short8*)&Bs[(h * 64 + tr) * LDT + tc]     = pack8(rb[h][0], rb[h][1]);
            *(short8*)&Bs[(h * 64 + tr) * LDT + tc + 8] = pack8(rb[h][2], rb[h][3]);
        }
        __syncthreads();
#pragma unroll
        for (int kk = 0; kk < 64; kk += 32) {
            short8 af[2], bf[4];
#pragma unroll
            for (int m = 0; m < 2; ++m)
                af[m] = *(const short8*)&As[(wr + m * 16 + fr) * LDT + kk + ke];
#pragma unroll
            for (int n = 0; n < 4; ++n)
                bf[n] = *(const short8*)&Bs[(wc + n * 16 + fr) * LDT + kk + ke];
#pragma unroll
            for (int m = 0; m < 2; ++m)
#pragma unroll
                for (int n = 0; n < 4; ++n)
                    acc[m][n] = __builtin_amdgcn_mfma_f32_16x16x32_bf16(
                        __builtin_bit_cast(bf16x8, af[m]),
                        __builtin_bit_cast(bf16x8, bf[n]),
                        acc[m][n], 0, 0, 0);
        }
    }
#pragma unroll
    for (int n = 0; n < 4; ++n) {
        const int col = bn + wc + n * 16 + fr;
        const float bv = bias[col];
#pragma unroll
        for (int m = 0; m < 2; ++m) {
            const int rbase = bm + wr + m * 16 + (lane >> 4) * 4;
#pragma unroll
            for (int r = 0; r < 4; ++r)
                out[(size_t)(rbase + r) * DIM + col] = acc[m][n][r] + bv;
        }
    }
}

// ---------------------------------------------------------------------------
// 3) walk kernel: 1 wave / 2 rows, gap-free chunks, 3-deep record ring
// ---------------------------------------------------------------------------
__global__ __launch_bounds__(64) void kwalk(const float* __restrict__ X, const float* __restrict__ vec,
                                            const uint4* __restrict__ recs, const int* __restrict__ cnts,
                                            const float* __restrict__ parts, int nparts,
                                            float* __restrict__ out) {
    __shared__ float2 rw[DIM + 2];
    const int pr   = blockIdx.x;
    const int lane = threadIdx.x;
    const int rA   = pr * 2, rB = pr * 2 + 1;

    {
        const float4* xa = (const float4*)(X + (size_t)rA * DIM);
        const float4* xb = (const float4*)(X + (size_t)rB * DIM);
        for (int c4 = lane; c4 < DIM / 4; c4 += 64) {
            const float4 a = xa[c4], b = xb[c4];
            rw[c4 * 4 + 0] = make_float2(a.x, b.x);
            rw[c4 * 4 + 1] = make_float2(a.y, b.y);
            rw[c4 * 4 + 2] = make_float2(a.z, b.z);
            rw[c4 * 4 + 3] = make_float2(a.w, b.w);
        }
        if (lane < 2) rw[DIM + lane] = make_float2(0.f, 0.f);
    }

    const int cnreg = cnts[lane < NSLOT ? lane : 0];

    for (int slot = 0; slot < NSLOT; ++slot) {
        if (slot == NW2) {      // between walks: yp = vec * yp
            const float4* v4 = (const float4*)vec;
            for (int c4 = lane; c4 < DIM / 4; c4 += 64) {
                const float4 v = v4[c4];
#pragma unroll
                for (int q = 0; q < 4; ++q) {
                    float2 tv = rw[c4 * 4 + q];
                    const float sc = (q == 0) ? v.x : (q == 1) ? v.y : (q == 2) ? v.z : v.w;
                    tv.x *= sc; tv.y *= sc;
                    rw[c4 * 4 + q] = tv;
                }
            }
        }
        const int nit = __shfl(cnreg, slot) >> 7;      // chunks (>=4)
        const uint4* base = recs + (size_t)slot * SLOT;

        // prologue: ring holds raw records for chunks 0,1,2
        uint4 r0A = base[lane],           r0B = base[64 + lane];
        uint4 r1A = base[128 + lane],     r1B = base[192 + lane];
        uint4 r2A = base[256 + lane],     r2B = base[256 + 64 + lane];

#pragma unroll 4
        for (int k = 0; k < nit; ++k) {
            // load records for chunk k+3 (clamped; dup loads never decoded)
            const int kc = (k + 3 < nit) ? (k + 3) : (nit - 1);
            const uint4 mA = base[(size_t)kc * 128 + lane];
            const uint4 mB = base[(size_t)kc * 128 + 64 + lane];

            // decode + gather + rotate + scatter chunk k (ring head).
            // Adjacent-chunk RAW through LDS: in-order per-wave DS pipe
            // (no barriers needed; validated R1-R3).
            const int   ia = (int)r0A.x, ja = (int)r0A.w;  // float2 byte offs
            const int   ib = (int)r0B.x, jb = (int)r0B.w;
            const float ca = bitf(r0A.y), sa = bitf(r0A.z);
            const float cb = bitf(r0B.y), sb = bitf(r0B.z);
            const float2 gai = ldrw(rw, ia), gaj = ldrw(rw, ja);
            const float2 gbi = ldrw(rw, ib), gbj = ldrw(rw, jb);

            float2 wia, wja, wib, wjb;
            wia.x = fmaf(ca, gai.x,  sa * gaj.x);
            wia.y = fmaf(ca, gai.y,  sa * gaj.y);
            wja.x = fmaf(ca, gaj.x, -sa * gai.x);
            wja.y = fmaf(ca, gaj.y, -sa * gai.y);
            wib.x = fmaf(cb, gbi.x,  sb * gbj.x);
            wib.y = fmaf(cb, gbi.y,  sb * gbj.y);
            wjb.x = fmaf(cb, gbj.x, -sb * gbi.x);
            wjb.y = fmaf(cb, gbj.y, -sb * gbi.y);
            strw(rw, ia, wia); strw(rw, ja, wja);
            strw(rw, ib, wib); strw(rw, jb, wjb);

            // rotate record ring
            r0A = r1A; r0B = r1B;
            r1A = r2A; r1B = r2B;
            r2A = mA;  r2B = mB;
        }
    }

    float4* oa = (float4*)(out + (size_t)rA * DIM);
    float4* ob = (float4*)(out + (size_t)rB * DIM);
    const size_t PS = (size_t)ROWS * DIM / 4;
    const float4* qa = (const float4*)parts + (size_t)rA * (DIM / 4);
    const float4* qb = (const float4*)parts + (size_t)rB * (DIM / 4);
    for (int c4 = lane; c4 < DIM / 4; c4 += 64) {
        const float2 p0 = rw[c4 * 4 + 0], p1 = rw[c4 * 4 + 1];
        const float2 p2 = rw[c4 * 4 + 2], p3 = rw[c4 * 4 + 3];
        float4 ta = oa[c4], tb = ob[c4];
        for (int p = 0; p < nparts; ++p) {
            const float4 a = qa[c4 + (size_t)p * PS];
            const float4 b = qb[c4 + (size_t)p * PS];
            ta.x += a.x; ta.y += a.y; ta.z += a.z; ta.w += a.w;
            tb.x += b.x; tb.y += b.y; tb.z += b.z; tb.w += b.w;
        }
        ta.x += p0.x; ta.y += p1.x; ta.z += p2.x; ta.w += p3.x;
        tb.x += p0.y; tb.y += p1.y; tb.z += p2.y; tb.w += p3.y;
        oa[c4] = ta; ob[c4] = tb;
    }
}

// ---------------------------------------------------------------------------
extern "C" void kernel_launch(void* const* d_in, const int* in_sizes, int n_in,
                              void* d_out, int out_size, void* d_ws, size_t ws_size,
                              hipStream_t stream) {
    const float* X    = (const float*)d_in[0];
    const float* W    = (const float*)d_in[1];
    const float* bias = (const float*)d_in[2];
    const float* vec  = (const float*)d_in[3];
    const int*   i1   = (const int*)d_in[4];
    const int*   j1   = (const int*)d_in[5];
    const float* c1   = (const float*)d_in[6];
    const float* s1   = (const float*)d_in[7];
    const int*   i2   = (const int*)d_in[8];
    const int*   j2   = (const int*)d_in[9];
    const float* c2   = (const float*)d_in[10];
    const float* s2   = (const float*)d_in[11];
    float* out = (float*)d_out;

    const size_t RD         = (size_t)ROWS * DIM * 4;            // 8 MiB
    const size_t WBB        = (size_t)DIM * DIM * 2;             // 32 MiB
    const size_t XBB        = (size_t)ROWS * DIM * 2;            // 4 MiB
    const size_t recs_bytes = (size_t)NSLOT * SLOT * 16;         // 6.29 MiB
    const size_t off_parts  = recs_bytes + 4096;

    // tiered Ksplit by workspace size
    int nks = 0;
    size_t off_wb = 0;
    {
        const size_t need4 = off_parts + 3 * RD + WBB + XBB;
        const size_t need2 = off_parts + 1 * RD + WBB + XBB;
        if      (ws_size >= need4) { nks = 4; off_wb = off_parts + 3 * RD; }
        else if (ws_size >= need2) { nks = 2; off_wb = off_parts + 1 * RD; }
    }

    uint4* recs  = (uint4*)d_ws;
    int*   cnts  = (int*)((char*)d_ws + recs_bytes);
    float* parts = (float*)((char*)d_ws + off_parts);
    short* wbuf  = (short*)((char*)d_ws + off_wb);
    short* xbuf  = (short*)((char*)d_ws + off_wb + WBB);
    const bool bf = (nks > 0);

    hipLaunchKernelGGL(kfused, dim3(NSLOT + (bf ? (NCVW + NCVX) : 0)), dim3(KT), 0, stream,
                       i1, j1, c1, s1, i2, j2, c2, s2, recs, cnts,
                       bf ? 1 : 0, W, X, wbuf, xbuf);
    if (bf)
        hipLaunchKernelGGL(kgemm_bf, dim3(128 * nks), dim3(256), 0, stream,
                           xbuf, wbuf, bias, out, parts, nks);
    else
        hipLaunchKernelGGL(kgemm_small, dim3(256), dim3(256), 0, stream, X, W, bias, out);
    hipLaunchKernelGGL(kwalk, dim3(ROWS / 2), dim3(64), 0, stream,
                       X, vec, recs, cnts, parts, bf ? (nks - 1) : 0, out);
}

// Round 15
// 240.219 us; speedup vs baseline: 1.4023x; 1.0575x over previous
//
#include <hip/hip_runtime.h>

// KacLayer: out[512][4096] = x @ W^T + b  +  Kac2( vec * Kac1( x ) )
//
//  kfused: blocks 0..11: per-8192-step window scheduler. Election assigns
//          dependency depth (= level); all chunks of one level are column-
//          DISJOINT (election winners of a round can't share a column).
//          Layout: per-WAVE contiguous chunk streams (chunk cl of level l ->
//          wave cl&3), gap-free, via packed-u8 prefix scan; per-slot
//          metadata = packed per-wave chunk counts per level. Records
//          scattered to global (pad-prefilled). Bit-exact reorder.
//          blocks 12..1163: fp32->bf16 convert of W and X into d_ws.
//  kgemm_bf: bf16 MFMA GEMM, 128x128 tile, BK=128, XOR-swizzled LDS,
//          runtime Ksplit (4 if ws allows, else 2) -> out + (nks-1) partials.
//  kwalk : 256 thr/block = 4 waves sharing ONE row-pair (float2 LDS).
//          Per level: waves process their own chunks in parallel (no RAW
//          inside a level), 3-deep contiguous record ring per wave; then a
//          light level-barrier (lgkmcnt(0)+s_barrier, NO vmcnt drain -> ring
//          prefetch stays in flight). Level boundaries carry the only true
//          dependencies. This converts wall = chunks x LDS-round-trip into
//          wall = chunks/4 x issue + levels x barrier.

#define DIM    4096
#define ROWS   512
#define NSTEPS 49152
#define WSTEPS 8192
#define NW2    (NSTEPS / WSTEPS)   // 6 windows per walk
#define NSLOT  (2 * NW2)           // 12 slots
#define NSG    16                  // rank subgroups (one per ksched wave)
#define CHUNK  128
#define WVN    4                   // kwalk waves per block
#define PWC    80                  // per-wave chunk capacity per slot
#define SLOTREC (WVN * PWC * CHUNK)   // 40960 records per slot
#define MAXR   96
#define PADI   4096
#define PADJ   4097
#define KT     1024                // scheduler threads
#define SPT    (WSTEPS / KT)       // 8 steps per thread
#define NCVW   1024                // W-convert blocks
#define NCVX   128                 // X-convert blocks

typedef short  short8 __attribute__((ext_vector_type(8)));
typedef __bf16 bf16x8 __attribute__((ext_vector_type(8)));
typedef float  f32x4  __attribute__((ext_vector_type(4)));

__device__ inline short f2bf(float f) {
    unsigned u = __builtin_bit_cast(unsigned, f);
    u += 0x7FFFu + ((u >> 16) & 1u);
    return (short)(u >> 16);
}
__device__ inline short8 pack8(float4 a, float4 b) {
    short8 r;
    r[0] = f2bf(a.x); r[1] = f2bf(a.y); r[2] = f2bf(a.z); r[3] = f2bf(a.w);
    r[4] = f2bf(b.x); r[5] = f2bf(b.y); r[6] = f2bf(b.z); r[7] = f2bf(b.w);
    return r;
}
__device__ inline float bitf(unsigned u) { return __builtin_bit_cast(float, u); }
__device__ inline float2 ldrw(const float2* rw, int boff) {
    return *(const float2*)((const char*)rw + boff);
}
__device__ inline void strw(float2* rw, int boff, float2 v) {
    *(float2*)((char*)rw + boff) = v;
}

// ---------------------------------------------------------------------------
// 1) fused scheduler (blocks 0..NSLOT-1) + bf16 convert (blocks NSLOT..)
// ---------------------------------------------------------------------------
__global__ __launch_bounds__(KT) void kfused(
    const int* __restrict__ i1, const int* __restrict__ j1,
    const float* __restrict__ c1, const float* __restrict__ s1,
    const int* __restrict__ i2, const int* __restrict__ j2,
    const float* __restrict__ c2, const float* __restrict__ s2,
    uint4* __restrict__ recs, int* __restrict__ nlvls, unsigned* __restrict__ lvmeta_g,
    int doconv, const float* __restrict__ W, const float* __restrict__ X,
    short* __restrict__ wb, short* __restrict__ xb) {

    // ---------------- convert path ----------------
    if (blockIdx.x >= NSLOT) {
        if (!doconv) return;
        const int cb = blockIdx.x - NSLOT;
        const float* src; short* dst; size_t base;
        if (cb < NCVW) { src = W; dst = wb; base = (size_t)cb * 16384; }
        else           { src = X; dst = xb; base = (size_t)(cb - NCVW) * 16384; }
        const size_t o = base + (size_t)threadIdx.x * 16;
        const float4* s4 = (const float4*)(src + o);
        const float4 a0 = s4[0], a1 = s4[1], a2 = s4[2], a3 = s4[3];
        *(short8*)(dst + o)     = pack8(a0, a1);
        *(short8*)(dst + o + 8) = pack8(a2, a3);
        return;
    }

    // ---------------- scheduler path ----------------
    __shared__ unsigned tbl[DIM];          // election keys      (16 KB)
    __shared__ unsigned spair[WSTEPS];     // li | lj<<16        (32 KB)
    __shared__ unsigned lvrk[WSTEPS];      // rank<<8 | level    (32 KB)
    __shared__ int lcnt[MAXR * NSG];       // per-(level,wave) counters (6 KB)
    __shared__ unsigned lvpk[MAXR], wvbase[MAXR];
    __shared__ int nlvlsh;

    const int b    = blockIdx.x;           // 0..11
    const int walk = b / NW2;
    const int w    = b % NW2;
    const int t    = threadIdx.x;
    const int gb   = w * WSTEPS;
    const int sg   = t >> 6;               // wave id 0..15

    const int*   I = walk ? i2 : i1;
    const int*   J = walk ? j2 : j1;
    const float* C = walk ? c2 : c1;
    const float* S = walk ? s2 : s1;

    uint4* slotp = recs + (size_t)b * SLOTREC;

    // prefill slot region with identity-pad records (coalesced)
    {
        const uint4 padrec = { (unsigned)(PADI * 8), 0x3F800000u, 0u, (unsigned)(PADJ * 8) };
        for (int k = t; k < SLOTREC; k += KT) slotp[k] = padrec;
    }
    for (int s = t; s < WSTEPS; s += KT)
        spair[s] = (unsigned)I[gb + s] | ((unsigned)J[gb + s] << 16);
    for (int k = t; k < DIM; k += KT) tbl[k] = 0xFFFFFFFFu;
    for (int k = t; k < MAXR * NSG; k += KT) lcnt[k] = 0;
    if (t == 0) nlvlsh = 1;
    __syncthreads();

    // ---- election: 2 barriers/round; level = DAG depth --------------------
    unsigned pmask = (1u << SPT) - 1u;
    for (int rr = 0; rr < MAXR; ++rr) {
        const unsigned rk = (unsigned)(MAXR - 1 - rr) << 13;
#pragma unroll
        for (int q = 0; q < SPT; ++q)
            if (pmask & (1u << q)) {
                const int s = q * KT + t;
                const unsigned sp = spair[s];
                const unsigned key = rk | (unsigned)s;
                atomicMin(&tbl[sp & 0xFFFFu], key);
                atomicMin(&tbl[sp >> 16], key);
            }
        __syncthreads();                                   // B1
#pragma unroll
        for (int q = 0; q < SPT; ++q)
            if (pmask & (1u << q)) {
                const int s = q * KT + t;
                const unsigned sp = spair[s];
                const unsigned key = rk | (unsigned)s;
                if (tbl[sp & 0xFFFFu] == key && tbl[sp >> 16] == key) {
                    const int rank = atomicAdd(&lcnt[rr * NSG + sg], 1);
                    lvrk[s] = ((unsigned)rank << 8) | (unsigned)rr;
                    pmask &= ~(1u << q);
                }
            }
        const int np = __syncthreads_count(pmask != 0);    // B2
        if (np == 0) break;
    }
    // safety net (statistically unreachable)
#pragma unroll
    for (int q = 0; q < SPT; ++q)
        if (pmask & (1u << q)) {
            const int s = q * KT + t;
            const int rank = atomicAdd(&lcnt[(MAXR - 1) * NSG + sg], 1);
            lvrk[s] = ((unsigned)rank << 8) | (unsigned)(MAXR - 1);
        }
    __syncthreads();

    // ---- layout: per-level per-wave chunk streams -------------------------
    if (t < MAXR) {
        int run = 0;
        for (int g = 0; g < NSG; ++g) {
            const int v = lcnt[t * NSG + g];
            lcnt[t * NSG + g] = run;
            run += v;
        }
        const int nch = (run + 127) >> 7;
        unsigned pk = 0;
#pragma unroll
        for (int wv = 0; wv < WVN; ++wv)
            pk |= (unsigned)((nch + (WVN - 1 - wv)) >> 2) << (8 * wv);
        lvpk[t] = pk;
        if (run > 0) atomicMax(&nlvlsh, t + 1);
    }
    __syncthreads();
    // packed-u8 exclusive prefix over 96 levels (per-wave stream bases)
    if (t < 64) {
        const int l = t;
        const unsigned w1 = lvpk[l];
        unsigned x1 = w1;
        for (int off = 1; off < 64; off <<= 1) {
            const unsigned v = (unsigned)__shfl_up((int)x1, off);
            if (l >= off) x1 += v;
        }
        wvbase[l] = x1 - w1;
        const unsigned seg1 = (unsigned)__shfl((int)x1, 63);
        const int l2 = 64 + (l & 31);
        const unsigned w2 = lvpk[l2];
        unsigned x2 = w2;
        for (int off = 1; off < 32; off <<= 1) {
            const unsigned v = (unsigned)__shfl_up((int)x2, off);
            if ((l & 31) >= off) x2 += v;
        }
        if (l < 32) wvbase[l2] = seg1 + x2 - w2;
    }
    __syncthreads();
    if (t == 0) nlvls[b] = nlvlsh;
    if (t < MAXR) lvmeta_g[b * MAXR + t] = lvpk[t];

    // ---- record emission (float2 byte offsets = idx*8) --------------------
#pragma unroll
    for (int q = 0; q < SPT; ++q) {
        const int s = q * KT + t;
        const unsigned v = lvrk[s];
        const int lvl  = (int)(v & 0xFFu);
        const int rank = (int)(v >> 8) + lcnt[lvl * NSG + sg];
        const int cl   = rank >> 7;            // chunk within level
        const int pos  = rank & 127;
        const int wv2  = cl & (WVN - 1);       // owning wave
        const int wc   = cl >> 2;              // wave-local chunk in level
        const int pch  = (int)((wvbase[lvl] >> (8 * wv2)) & 0xFFu) + wc;
        if (pch < PWC) {
            const unsigned sp = spair[s];
            const int g = gb + s;
            uint4 r;
            r.x = (sp & 0xFFFFu) * 8u;
            r.y = __builtin_bit_cast(unsigned, C[g]);
            r.z = __builtin_bit_cast(unsigned, S[g]);
            r.w = (sp >> 16) * 8u;
            slotp[((size_t)wv2 * PWC + pch) * CHUNK + pos] = r;
        }
    }
}

// ---------------------------------------------------------------------------
// 2a) bf16 GEMM: 128x128 tile, BK=128, runtime Ksplit nks
// ---------------------------------------------------------------------------
__global__ __launch_bounds__(256) void kgemm_bf(const short* __restrict__ Xb, const short* __restrict__ Wb,
                                                const float* __restrict__ bias, float* __restrict__ out,
                                                float* __restrict__ parts, int nks) {
    __shared__ short As[128 * 128];
    __shared__ short Bs[128 * 128];
    const int bid  = blockIdx.x;
    const int ks   = bid % nks;
    const int tile = bid / nks;                // 0..127
    const int bm   = (tile >> 5) * 128;
    const int bn   = (tile & 31) * 128;
    const int tid  = threadIdx.x;
    const int lane = tid & 63;
    const int wv   = tid >> 6;
    const int wr   = (wv >> 1) * 64;
    const int wc   = (wv & 1) * 64;
    const int fr   = lane & 15;
    const int ke   = (lane >> 4) * 8;

    f32x4 acc[4][4];
#pragma unroll
    for (int m = 0; m < 4; ++m)
#pragma unroll
        for (int n = 0; n < 4; ++n) acc[m][n] = (f32x4){0.f, 0.f, 0.f, 0.f};

    const int tr2 = tid >> 1;                  // staging row 0..127
    const int hh  = tid & 1;                   // 64-elem half
    const int wm  = tr2 & 7;                   // swizzle mask
    const short* gxa = Xb + (size_t)(bm + tr2) * DIM + hh * 64;
    const short* gwb = Wb + (size_t)(bn + tr2) * DIM + hh * 64;

    const int nkt = DIM / 128 / nks;
    const int kbase = ks * (DIM / nks);
    for (int kt = 0; kt < nkt; ++kt) {
        const int k0 = kbase + kt * 128;
        short8 ar[8], br[8];
#pragma unroll
        for (int q = 0; q < 8; ++q) ar[q] = *(const short8*)(gxa + k0 + q * 8);
#pragma unroll
        for (int q = 0; q < 8; ++q) br[q] = *(const short8*)(gwb + k0 + q * 8);
        __syncthreads();                       // previous tile's reads done
#pragma unroll
        for (int q = 0; q < 8; ++q) {
            const int sl = (hh * 8 + q) ^ wm;  // XOR-swizzled 16B slot
            *(short8*)&As[tr2 * 128 + sl * 8] = ar[q];
            *(short8*)&Bs[tr2 * 128 + sl * 8] = br[q];
        }
        __syncthreads();
#pragma unroll
        for (int kk = 0; kk < 128; kk += 32) {
            const int sbase = (kk + ke) >> 3;
            short8 af[4], bf[4];
#pragma unroll
            for (int m = 0; m < 4; ++m) {
                const int R = wr + m * 16 + fr;
                af[m] = *(const short8*)&As[R * 128 + ((sbase ^ (R & 7)) << 3)];
            }
#pragma unroll
            for (int n = 0; n < 4; ++n) {
                const int R = wc + n * 16 + fr;
                bf[n] = *(const short8*)&Bs[R * 128 + ((sbase ^ (R & 7)) << 3)];
            }
#pragma unroll
            for (int m = 0; m < 4; ++m)
#pragma unroll
                for (int n = 0; n < 4; ++n)
                    acc[m][n] = __builtin_amdgcn_mfma_f32_16x16x32_bf16(
                        __builtin_bit_cast(bf16x8, af[m]),
                        __builtin_bit_cast(bf16x8, bf[n]),
                        acc[m][n], 0, 0, 0);
        }
    }
    float* dst = ks ? (parts + (size_t)(ks - 1) * ROWS * DIM) : out;
#pragma unroll
    for (int n = 0; n < 4; ++n) {
        const int col = bn + wc + n * 16 + fr;
        const float bv = ks ? 0.f : bias[col];
#pragma unroll
        for (int m = 0; m < 4; ++m) {
            const int rbase = bm + wr + m * 16 + (lane >> 4) * 4;
#pragma unroll
            for (int r = 0; r < 4; ++r)
                dst[(size_t)(rbase + r) * DIM + col] = acc[m][n][r] + bv;
        }
    }
}

// ---------------------------------------------------------------------------
// 2b) fallback GEMM: fp32 staging, BM=64 BN=128, full K, 256 thr
// ---------------------------------------------------------------------------
#define LDT 72
__global__ __launch_bounds__(256) void kgemm_small(const float* __restrict__ X, const float* __restrict__ W,
                                                   const float* __restrict__ bias, float* __restrict__ out) {
    __shared__ short As[64 * LDT];
    __shared__ short Bs[128 * LDT];
    const int tid  = threadIdx.x;
    const int bn   = (blockIdx.x & 31) * 128;
    const int bm   = (blockIdx.x >> 5) * 64;
    const int lane = tid & 63;
    const int wv   = tid >> 6;
    const int wr   = (wv >> 1) * 32;
    const int wc   = (wv & 1) * 64;
    const int fr   = lane & 15;
    const int ke   = (lane >> 4) * 8;

    f32x4 acc[2][4];
#pragma unroll
    for (int m = 0; m < 2; ++m)
#pragma unroll
        for (int n = 0; n < 4; ++n) acc[m][n] = (f32x4){0.f, 0.f, 0.f, 0.f};

    const int tr = tid >> 2;
    const int tc = (tid & 3) << 4;

    for (int kt = 0; kt < DIM / 64; ++kt) {
        const int k0 = kt * 64;
        float4 ra[4], rb[2][4];
        {
            const float4* ga = (const float4*)(X + (size_t)(bm + tr) * DIM + k0 + tc);
#pragma unroll
            for (int q = 0; q < 4; ++q) ra[q] = ga[q];
#pragma unroll
            for (int h = 0; h < 2; ++h) {
                const float4* gw = (const float4*)(W + (size_t)(bn + h * 64 + tr) * DIM + k0 + tc);
#pragma unroll
                for (int q = 0; q < 4; ++q) rb[h][q] = gw[q];
            }
        }
        __syncthreads();
        *(short8*)&As[tr * LDT + tc]     = pack8(ra[0], ra[1]);
        *(short8*)&As[tr * LDT + tc + 8] = pack8(ra[2], ra[3]);
#pragma unroll
        for (int h = 0; h < 2; ++h) {
            *(short8*)&Bs[(h * 64 + tr) * LDT + tc]     = pack8(rb[h][0], rb[h][1]);
            *(short8*)&Bs[(h * 64 + tr) * LDT + tc + 8] = pack8(rb[h][2], rb[h][3]);
        }
        __syncthreads();
#pragma unroll
        for (int kk = 0; kk < 64; kk += 32) {
            short8 af[2], bf[4];
#pragma unroll
            for (int m = 0; m < 2; ++m)
                af[m] = *(const short8*)&As[(wr + m * 16 + fr) * LDT + kk + ke];
#pragma unroll
            for (int n = 0; n < 4; ++n)
                bf[n] = *(const short8*)&Bs[(wc + n * 16 + fr) * LDT + kk + ke];
#pragma unroll
            for (int m = 0; m < 2; ++m)
#pragma unroll
                for (int n = 0; n < 4; ++n)
                    acc[m][n] = __builtin_amdgcn_mfma_f32_16x16x32_bf16(
                        __builtin_bit_cast(bf16x8, af[m]),
                        __builtin_bit_cast(bf16x8, bf[n]),
                        acc[m][n], 0, 0, 0);
        }
    }
#pragma unroll
    for (int n = 0; n < 4; ++n) {
        const int col = bn + wc + n * 16 + fr;
        const float bv = bias[col];
#pragma unroll
        for (int m = 0; m < 2; ++m) {
            const int rbase = bm + wr + m * 16 + (lane >> 4) * 4;
#pragma unroll
            for (int r = 0; r < 4; ++r)
                out[(size_t)(rbase + r) * DIM + col] = acc[m][n][r] + bv;
        }
    }
}

// ---------------------------------------------------------------------------
// 3) walk kernel: 4 waves / row-pair, level-parallel chunks, light barriers
// ---------------------------------------------------------------------------
__global__ __launch_bounds__(256) void kwalk(const float* __restrict__ X, const float* __restrict__ vec,
                                             const uint4* __restrict__ recs, const int* __restrict__ nlvls,
                                             const unsigned* __restrict__ lvmeta_g,
                                             const float* __restrict__ parts, int nparts,
                                             float* __restrict__ out) {
    __shared__ float2 rw[DIM + 2];
    __shared__ unsigned lvm[MAXR];
    const int tid  = threadIdx.x;
    const int wv   = tid >> 6;
    const int lane = tid & 63;
    const int pr   = blockIdx.x;
    const int rA   = pr * 2, rB = pr * 2 + 1;

    {
        const float4* xa = (const float4*)(X + (size_t)rA * DIM);
        const float4* xb = (const float4*)(X + (size_t)rB * DIM);
        for (int c4 = tid; c4 < DIM / 4; c4 += 256) {
            const float4 a = xa[c4], b = xb[c4];
            rw[c4 * 4 + 0] = make_float2(a.x, b.x);
            rw[c4 * 4 + 1] = make_float2(a.y, b.y);
            rw[c4 * 4 + 2] = make_float2(a.z, b.z);
            rw[c4 * 4 + 3] = make_float2(a.w, b.w);
        }
        if (tid < 2) rw[DIM + tid] = make_float2(0.f, 0.f);
    }

    for (int slot = 0; slot < NSLOT; ++slot) {
        if (slot == NW2) {      // between walks: yp = vec * yp (prev slot's
            __syncthreads();    // level-barrier synced; extra barrier for init case)
            const float4* v4 = (const float4*)vec;
            for (int c4 = tid; c4 < DIM / 4; c4 += 256) {
                const float4 v = v4[c4];
#pragma unroll
                for (int q = 0; q < 4; ++q) {
                    float2 tv = rw[c4 * 4 + q];
                    const float sc = (q == 0) ? v.x : (q == 1) ? v.y : (q == 2) ? v.z : v.w;
                    tv.x *= sc; tv.y *= sc;
                    rw[c4 * 4 + q] = tv;
                }
            }
        }
        if (tid < MAXR) lvm[tid] = lvmeta_g[slot * MAXR + tid];
        const int nlvl = nlvls[slot];
        __syncthreads();

        const uint4* wbase = recs + (size_t)slot * SLOTREC + (size_t)wv * (PWC * CHUNK);
        // 3-deep record ring over this wave's contiguous stream
        uint4 r0A = wbase[lane],       r0B = wbase[64 + lane];
        uint4 r1A = wbase[128 + lane], r1B = wbase[192 + lane];
        uint4 r2A = wbase[256 + lane], r2B = wbase[320 + lane];
        int t = 0;

        for (int lvl = 0; lvl < nlvl; ++lvl) {
            const int n = (int)((lvm[lvl] >> (wv * 8)) & 0xFFu);
            for (int it = 0; it < n; ++it) {
                int kc = t + 3; if (kc > PWC - 1) kc = PWC - 1;
                const uint4 mA = wbase[(size_t)kc * CHUNK + lane];
                const uint4 mB = wbase[(size_t)kc * CHUNK + 64 + lane];

                // chunks within a level are column-disjoint: no intra-level
                // ordering needed; decode+gather+rotate+scatter chunk t.
                const int   ia = (int)r0A.x, ja = (int)r0A.w;
                const int   ib = (int)r0B.x, jb = (int)r0B.w;
                const float ca = bitf(r0A.y), sa = bitf(r0A.z);
                const float cb = bitf(r0B.y), sb = bitf(r0B.z);
                const float2 gai = ldrw(rw, ia), gaj = ldrw(rw, ja);
                const float2 gbi = ldrw(rw, ib), gbj = ldrw(rw, jb);

                float2 wia, wja, wib, wjb;
                wia.x = fmaf(ca, gai.x,  sa * gaj.x);
                wia.y = fmaf(ca, gai.y,  sa * gaj.y);
                wja.x = fmaf(ca, gaj.x, -sa * gai.x);
                wja.y = fmaf(ca, gaj.y, -sa * gai.y);
                wib.x = fmaf(cb, gbi.x,  sb * gbj.x);
                wib.y = fmaf(cb, gbi.y,  sb * gbj.y);
                wjb.x = fmaf(cb, gbj.x, -sb * gbi.x);
                wjb.y = fmaf(cb, gbj.y, -sb * gbi.y);
                strw(rw, ia, wia); strw(rw, ja, wja);
                strw(rw, ib, wib); strw(rw, jb, wjb);

                r0A = r1A; r0B = r1B;
                r1A = r2A; r1B = r2B;
                r2A = mA;  r2B = mB;
                ++t;
            }
            // light level barrier: drain LDS ops, keep record loads in flight
            __builtin_amdgcn_sched_barrier(0);
            asm volatile("s_waitcnt lgkmcnt(0)" ::: "memory");
            __builtin_amdgcn_s_barrier();
            __builtin_amdgcn_sched_barrier(0);
        }
    }

    float4* oa = (float4*)(out + (size_t)rA * DIM);
    float4* ob = (float4*)(out + (size_t)rB * DIM);
    const size_t PS = (size_t)ROWS * DIM / 4;
    const float4* qa = (const float4*)parts + (size_t)rA * (DIM / 4);
    const float4* qb = (const float4*)parts + (size_t)rB * (DIM / 4);
    for (int c4 = tid; c4 < DIM / 4; c4 += 256) {
        const float2 p0 = rw[c4 * 4 + 0], p1 = rw[c4 * 4 + 1];
        const float2 p2 = rw[c4 * 4 + 2], p3 = rw[c4 * 4 + 3];
        float4 ta = oa[c4], tb = ob[c4];
        for (int p = 0; p < nparts; ++p) {
            const float4 a = qa[c4 + (size_t)p * PS];
            const float4 b = qb[c4 + (size_t)p * PS];
            ta.x += a.x; ta.y += a.y; ta.z += a.z; ta.w += a.w;
            tb.x += b.x; tb.y += b.y; tb.z += b.z; tb.w += b.w;
        }
        ta.x += p0.x; ta.y += p1.x; ta.z += p2.x; ta.w += p3.x;
        tb.x += p0.y; tb.y += p1.y; tb.z += p2.y; tb.w += p3.y;
        oa[c4] = ta; ob[c4] = tb;
    }
}

// ---------------------------------------------------------------------------
extern "C" void kernel_launch(void* const* d_in, const int* in_sizes, int n_in,
                              void* d_out, int out_size, void* d_ws, size_t ws_size,
                              hipStream_t stream) {
    const float* X    = (const float*)d_in[0];
    const float* W    = (const float*)d_in[1];
    const float* bias = (const float*)d_in[2];
    const float* vec  = (const float*)d_in[3];
    const int*   i1   = (const int*)d_in[4];
    const int*   j1   = (const int*)d_in[5];
    const float* c1   = (const float*)d_in[6];
    const float* s1   = (const float*)d_in[7];
    const int*   i2   = (const int*)d_in[8];
    const int*   j2   = (const int*)d_in[9];
    const float* c2   = (const float*)d_in[10];
    const float* s2   = (const float*)d_in[11];
    float* out = (float*)d_out;

    const size_t RD         = (size_t)ROWS * DIM * 4;            // 8 MiB
    const size_t WBB        = (size_t)DIM * DIM * 2;             // 32 MiB
    const size_t XBB        = (size_t)ROWS * DIM * 2;            // 4 MiB
    const size_t recs_bytes = (size_t)NSLOT * SLOTREC * 16;      // 7.86 MiB
    const size_t off_lvm    = recs_bytes + 1024;
    const size_t off_parts  = recs_bytes + 16384;

    // tiered Ksplit by workspace size
    int nks = 0;
    size_t off_wb = 0;
    {
        const size_t need4 = off_parts + 3 * RD + WBB + XBB;
        const size_t need2 = off_parts + 1 * RD + WBB + XBB;
        if      (ws_size >= need4) { nks = 4; off_wb = off_parts + 3 * RD; }
        else if (ws_size >= need2) { nks = 2; off_wb = off_parts + 1 * RD; }
    }

    uint4*    recs   = (uint4*)d_ws;
    int*      nlvlsb = (int*)((char*)d_ws + recs_bytes);
    unsigned* lvmeta = (unsigned*)((char*)d_ws + off_lvm);
    float*    parts  = (float*)((char*)d_ws + off_parts);
    short*    wbuf   = (short*)((char*)d_ws + off_wb);
    short*    xbuf   = (short*)((char*)d_ws + off_wb + WBB);
    const bool bf = (nks > 0);

    hipLaunchKernelGGL(kfused, dim3(NSLOT + (bf ? (NCVW + NCVX) : 0)), dim3(KT), 0, stream,
                       i1, j1, c1, s1, i2, j2, c2, s2, recs, nlvlsb, lvmeta,
                       bf ? 1 : 0, W, X, wbuf, xbuf);
    if (bf)
        hipLaunchKernelGGL(kgemm_bf, dim3(128 * nks), dim3(256), 0, stream,
                           xbuf, wbuf, bias, out, parts, nks);
    else
        hipLaunchKernelGGL(kgemm_small, dim3(256), dim3(256), 0, stream, X, W, bias, out);
    hipLaunchKernelGGL(kwalk, dim3(ROWS / 2), dim3(256), 0, stream,
                       X, vec, recs, nlvlsb, lvmeta, parts, bf ? (nks - 1) : 0, out);
}

// Round 16
// 226.287 us; speedup vs baseline: 1.4887x; 1.0616x over previous
//
#include <hip/hip_runtime.h>

// KacLayer: out[512][4096] = x @ W^T + b  +  Kac2( vec * Kac1( x ) )
//
//  kfused: blocks 0..11: per-8192-step window scheduler. Election assigns
//          dependency depth (= level); chunks within a level are column-
//          disjoint. Layout: per-WAVE contiguous chunk streams. Levels with
//          <=2 chunks are SERIAL (all chunks -> wave 0); consecutive serial
//          levels skip the inter-level barrier (flag bit31 of lvmeta) --
//          wave0's in-order DS pipe handles the RAW (R14-validated).
//          Records scattered to global (pad-prefilled). Bit-exact reorder.
//          blocks 12..1163: fp32->bf16 convert of W and X into d_ws.
//  kgemm_bf: bf16 MFMA GEMM, 128x128 tile, BK=64, staging via
//          global_load_lds (1KB coalesced per instruction), pre-swizzled
//          global source + swizzled ds_read_b128 (bank-conflict-free),
//          runtime Ksplit (4 if ws allows, else 2) -> out + (nks-1) partials.
//  kwalk : 256 thr/block = 4 waves sharing ONE row-pair (float2 LDS).
//          Per level: parallel levels split chunks across waves + light
//          barrier; serial levels run on wave0 with barriers elided inside
//          serial runs. 3-deep per-wave record ring hides record-load latency.

#define DIM    4096
#define ROWS   512
#define NSTEPS 49152
#define WSTEPS 8192
#define NW2    (NSTEPS / WSTEPS)   // 6 windows per walk
#define NSLOT  (2 * NW2)           // 12 slots
#define NSG    16                  // rank subgroups (one per ksched wave)
#define CHUNK  128
#define WVN    4                   // kwalk waves per block
#define PWC    96                  // per-wave chunk capacity per slot
#define SLOTREC (WVN * PWC * CHUNK)   // 49152 records per slot
#define MAXR   96
#define PADI   4096
#define PADJ   4097
#define KT     1024                // scheduler threads
#define SPT    (WSTEPS / KT)       // 8 steps per thread
#define NCVW   1024                // W-convert blocks
#define NCVX   128                 // X-convert blocks

typedef short  short8 __attribute__((ext_vector_type(8)));
typedef __bf16 bf16x8 __attribute__((ext_vector_type(8)));
typedef float  f32x4  __attribute__((ext_vector_type(4)));

__device__ inline short f2bf(float f) {
    unsigned u = __builtin_bit_cast(unsigned, f);
    u += 0x7FFFu + ((u >> 16) & 1u);
    return (short)(u >> 16);
}
__device__ inline short8 pack8(float4 a, float4 b) {
    short8 r;
    r[0] = f2bf(a.x); r[1] = f2bf(a.y); r[2] = f2bf(a.z); r[3] = f2bf(a.w);
    r[4] = f2bf(b.x); r[5] = f2bf(b.y); r[6] = f2bf(b.z); r[7] = f2bf(b.w);
    return r;
}
__device__ inline float bitf(unsigned u) { return __builtin_bit_cast(float, u); }
__device__ inline float2 ldrw(const float2* rw, int boff) {
    return *(const float2*)((const char*)rw + boff);
}
__device__ inline void strw(float2* rw, int boff, float2 v) {
    *(float2*)((char*)rw + boff) = v;
}
// async global->LDS, 16B per lane, dst = wave-uniform base + lane*16
__device__ inline void gl16(const short* g, short* l) {
    __builtin_amdgcn_global_load_lds((const __attribute__((address_space(1))) unsigned*)g,
                                     (__attribute__((address_space(3))) unsigned*)l, 16, 0, 0);
}

// ---------------------------------------------------------------------------
// 1) fused scheduler (blocks 0..NSLOT-1) + bf16 convert (blocks NSLOT..)
// ---------------------------------------------------------------------------
__global__ __launch_bounds__(KT) void kfused(
    const int* __restrict__ i1, const int* __restrict__ j1,
    const float* __restrict__ c1, const float* __restrict__ s1,
    const int* __restrict__ i2, const int* __restrict__ j2,
    const float* __restrict__ c2, const float* __restrict__ s2,
    uint4* __restrict__ recs, int* __restrict__ nlvls, unsigned* __restrict__ lvmeta_g,
    int doconv, const float* __restrict__ W, const float* __restrict__ X,
    short* __restrict__ wb, short* __restrict__ xb) {

    // ---------------- convert path ----------------
    if (blockIdx.x >= NSLOT) {
        if (!doconv) return;
        const int cb = blockIdx.x - NSLOT;
        const float* src; short* dst; size_t base;
        if (cb < NCVW) { src = W; dst = wb; base = (size_t)cb * 16384; }
        else           { src = X; dst = xb; base = (size_t)(cb - NCVW) * 16384; }
        const size_t o = base + (size_t)threadIdx.x * 16;
        const float4* s4 = (const float4*)(src + o);
        const float4 a0 = s4[0], a1 = s4[1], a2 = s4[2], a3 = s4[3];
        *(short8*)(dst + o)     = pack8(a0, a1);
        *(short8*)(dst + o + 8) = pack8(a2, a3);
        return;
    }

    // ---------------- scheduler path ----------------
    __shared__ unsigned tbl[DIM];          // election keys      (16 KB)
    __shared__ unsigned spair[WSTEPS];     // li | lj<<16        (32 KB)
    __shared__ unsigned lvrk[WSTEPS];      // rank<<8 | level    (32 KB)
    __shared__ int lcnt[MAXR * NSG];       // per-(level,wave) counters (6 KB)
    __shared__ unsigned lvpk[MAXR], wvbase[MAXR];
    __shared__ unsigned char serf[MAXR];
    __shared__ int nlvlsh;

    const int b    = blockIdx.x;           // 0..11
    const int walk = b / NW2;
    const int w    = b % NW2;
    const int t    = threadIdx.x;
    const int gb   = w * WSTEPS;
    const int sg   = t >> 6;               // wave id 0..15

    const int*   I = walk ? i2 : i1;
    const int*   J = walk ? j2 : j1;
    const float* C = walk ? c2 : c1;
    const float* S = walk ? s2 : s1;

    uint4* slotp = recs + (size_t)b * SLOTREC;

    // prefill slot region with identity-pad records (coalesced)
    {
        const uint4 padrec = { (unsigned)(PADI * 8), 0x3F800000u, 0u, (unsigned)(PADJ * 8) };
        for (int k = t; k < SLOTREC; k += KT) slotp[k] = padrec;
    }
    for (int s = t; s < WSTEPS; s += KT)
        spair[s] = (unsigned)I[gb + s] | ((unsigned)J[gb + s] << 16);
    for (int k = t; k < DIM; k += KT) tbl[k] = 0xFFFFFFFFu;
    for (int k = t; k < MAXR * NSG; k += KT) lcnt[k] = 0;
    if (t < MAXR) serf[t] = 0;
    if (t == 0) nlvlsh = 1;
    __syncthreads();

    // ---- election: 2 barriers/round; level = DAG depth --------------------
    unsigned pmask = (1u << SPT) - 1u;
    for (int rr = 0; rr < MAXR; ++rr) {
        const unsigned rk = (unsigned)(MAXR - 1 - rr) << 13;
#pragma unroll
        for (int q = 0; q < SPT; ++q)
            if (pmask & (1u << q)) {
                const int s = q * KT + t;
                const unsigned sp = spair[s];
                const unsigned key = rk | (unsigned)s;
                atomicMin(&tbl[sp & 0xFFFFu], key);
                atomicMin(&tbl[sp >> 16], key);
            }
        __syncthreads();                                   // B1
#pragma unroll
        for (int q = 0; q < SPT; ++q)
            if (pmask & (1u << q)) {
                const int s = q * KT + t;
                const unsigned sp = spair[s];
                const unsigned key = rk | (unsigned)s;
                if (tbl[sp & 0xFFFFu] == key && tbl[sp >> 16] == key) {
                    const int rank = atomicAdd(&lcnt[rr * NSG + sg], 1);
                    lvrk[s] = ((unsigned)rank << 8) | (unsigned)rr;
                    pmask &= ~(1u << q);
                }
            }
        const int np = __syncthreads_count(pmask != 0);    // B2
        if (np == 0) break;
    }
    // safety net (statistically unreachable)
#pragma unroll
    for (int q = 0; q < SPT; ++q)
        if (pmask & (1u << q)) {
            const int s = q * KT + t;
            const int rank = atomicAdd(&lcnt[(MAXR - 1) * NSG + sg], 1);
            lvrk[s] = ((unsigned)rank << 8) | (unsigned)(MAXR - 1);
        }
    __syncthreads();

    // ---- layout: per-level per-wave chunk streams; small levels serial ----
    if (t < MAXR) {
        int run = 0;
        for (int g = 0; g < NSG; ++g) {
            const int v = lcnt[t * NSG + g];
            lcnt[t * NSG + g] = run;
            run += v;
        }
        const int nch = (run + 127) >> 7;
        unsigned pk = 0;
        if (run > 0 && nch <= 2) {             // serial level: all on wave 0
            serf[t] = 1;
            pk = (unsigned)nch;
        } else {
#pragma unroll
            for (int wv = 0; wv < WVN; ++wv)
                pk |= (unsigned)((nch + (WVN - 1 - wv)) >> 2) << (8 * wv);
        }
        lvpk[t] = pk;
        if (run > 0) atomicMax(&nlvlsh, t + 1);
    }
    __syncthreads();
    // packed-u8 exclusive prefix over 96 levels (per-wave stream bases)
    if (t < 64) {
        const int l = t;
        const unsigned w1 = lvpk[l];
        unsigned x1 = w1;
        for (int off = 1; off < 64; off <<= 1) {
            const unsigned v = (unsigned)__shfl_up((int)x1, off);
            if (l >= off) x1 += v;
        }
        wvbase[l] = x1 - w1;
        const unsigned seg1 = (unsigned)__shfl((int)x1, 63);
        const int l2 = 64 + (l & 31);
        const unsigned w2 = lvpk[l2];
        unsigned x2 = w2;
        for (int off = 1; off < 32; off <<= 1) {
            const unsigned v = (unsigned)__shfl_up((int)x2, off);
            if ((l & 31) >= off) x2 += v;
        }
        if (l < 32) wvbase[l2] = seg1 + x2 - w2;
    }
    __syncthreads();
    // skip-barrier flag: level l serial AND level l+1 serial
    if (t < MAXR - 1) {
        if (serf[t] && serf[t + 1]) lvpk[t] |= 0x80000000u;
    }
    __syncthreads();
    if (t == 0) nlvls[b] = nlvlsh;
    if (t < MAXR) lvmeta_g[b * MAXR + t] = lvpk[t];

    // ---- record emission (float2 byte offsets = idx*8) --------------------
#pragma unroll
    for (int q = 0; q < SPT; ++q) {
        const int s = q * KT + t;
        const unsigned v = lvrk[s];
        const int lvl  = (int)(v & 0xFFu);
        const int rank = (int)(v >> 8) + lcnt[lvl * NSG + sg];
        const int cl   = rank >> 7;            // chunk within level
        const int pos  = rank & 127;
        int wv2, wc2;
        if (serf[lvl]) { wv2 = 0; wc2 = cl; }
        else           { wv2 = cl & (WVN - 1); wc2 = cl >> 2; }
        const int pch = (int)((wvbase[lvl] >> (8 * wv2)) & 0xFFu) + wc2;
        if (pch < PWC) {
            const unsigned sp = spair[s];
            const int g = gb + s;
            uint4 r;
            r.x = (sp & 0xFFFFu) * 8u;
            r.y = __builtin_bit_cast(unsigned, C[g]);
            r.z = __builtin_bit_cast(unsigned, S[g]);
            r.w = (sp >> 16) * 8u;
            slotp[((size_t)wv2 * PWC + pch) * CHUNK + pos] = r;
        }
    }
}

// ---------------------------------------------------------------------------
// 2a) bf16 GEMM: 128x128 tile, BK=64, global_load_lds staging, Ksplit nks
// ---------------------------------------------------------------------------
__global__ __launch_bounds__(256) void kgemm_bf(const short* __restrict__ Xb, const short* __restrict__ Wb,
                                                const float* __restrict__ bias, float* __restrict__ out,
                                                float* __restrict__ parts, int nks) {
    __shared__ short As[128 * 64];
    __shared__ short Bs[128 * 64];
    const int bid  = blockIdx.x;
    const int ks   = bid % nks;
    const int tile = bid / nks;                // 0..127
    const int bm   = (tile >> 5) * 128;
    const int bn   = (tile & 31) * 128;
    const int tid  = threadIdx.x;
    const int lane = tid & 63;
    const int wv   = tid >> 6;
    const int wr   = (wv >> 1) * 64;
    const int wc   = (wv & 1) * 64;
    const int fr   = lane & 15;
    const int ke   = (lane >> 4) * 8;

    f32x4 acc[4][4];
#pragma unroll
    for (int m = 0; m < 4; ++m)
#pragma unroll
        for (int n = 0; n < 4; ++n) acc[m][n] = (f32x4){0.f, 0.f, 0.f, 0.f};

    // staging: 8 x global_load_lds per wave per K-step (4 A + 4 B), 1KB each.
    // call q covers tile rows wv*32+q*8 .. +8; lane -> row wv*32+q*8+(lane>>3),
    // LDS slot lane&7; global col pre-swizzled: ((lane&7)^(row&7))*8.
    const int lrow = lane >> 3;
    const int scol = (((lane & 7) ^ (lrow & 7)) << 3);
    const short* gx = Xb + (size_t)(bm + wv * 32 + lrow) * DIM + scol;
    const short* gw = Wb + (size_t)(bn + wv * 32 + lrow) * DIM + scol;
    short* lA = As + wv * 2048;
    short* lB = Bs + wv * 2048;

    const int nkt   = (DIM / 64) / nks;        // 16 at nks=4
    const int kbase = ks * (DIM / nks);
    for (int kt = 0; kt < nkt; ++kt) {
        const int k0 = kbase + kt * 64;
        __syncthreads();                       // previous tile's LDS reads done
#pragma unroll
        for (int q = 0; q < 4; ++q) {
            gl16(gx + (size_t)(q * 8) * DIM + k0, lA + q * 512);
            gl16(gw + (size_t)(q * 8) * DIM + k0, lB + q * 512);
        }
        __syncthreads();                       // drains vmcnt -> tile ready
#pragma unroll
        for (int kk = 0; kk < 64; kk += 32) {
            const int sb = (kk + ke) >> 3;     // k slot 0..7
            short8 af[4], bf[4];
#pragma unroll
            for (int m = 0; m < 4; ++m) {
                const int R = wr + m * 16 + fr;
                af[m] = *(const short8*)&As[R * 64 + ((sb ^ (R & 7)) << 3)];
            }
#pragma unroll
            for (int n = 0; n < 4; ++n) {
                const int R = wc + n * 16 + fr;
                bf[n] = *(const short8*)&Bs[R * 64 + ((sb ^ (R & 7)) << 3)];
            }
#pragma unroll
            for (int m = 0; m < 4; ++m)
#pragma unroll
                for (int n = 0; n < 4; ++n)
                    acc[m][n] = __builtin_amdgcn_mfma_f32_16x16x32_bf16(
                        __builtin_bit_cast(bf16x8, af[m]),
                        __builtin_bit_cast(bf16x8, bf[n]),
                        acc[m][n], 0, 0, 0);
        }
    }
    float* dst = ks ? (parts + (size_t)(ks - 1) * ROWS * DIM) : out;
#pragma unroll
    for (int n = 0; n < 4; ++n) {
        const int col = bn + wc + n * 16 + fr;
        const float bv = ks ? 0.f : bias[col];
#pragma unroll
        for (int m = 0; m < 4; ++m) {
            const int rbase = bm + wr + m * 16 + (lane >> 4) * 4;
#pragma unroll
            for (int r = 0; r < 4; ++r)
                dst[(size_t)(rbase + r) * DIM + col] = acc[m][n][r] + bv;
        }
    }
}

// ---------------------------------------------------------------------------
// 2b) fallback GEMM: fp32 staging, BM=64 BN=128, full K, 256 thr
// ---------------------------------------------------------------------------
#define LDT 72
__global__ __launch_bounds__(256) void kgemm_small(const float* __restrict__ X, const float* __restrict__ W,
                                                   const float* __restrict__ bias, float* __restrict__ out) {
    __shared__ short As[64 * LDT];
    __shared__ short Bs[128 * LDT];
    const int tid  = threadIdx.x;
    const int bn   = (blockIdx.x & 31) * 128;
    const int bm   = (blockIdx.x >> 5) * 64;
    const int lane = tid & 63;
    const int wv   = tid >> 6;
    const int wr   = (wv >> 1) * 32;
    const int wc   = (wv & 1) * 64;
    const int fr   = lane & 15;
    const int ke   = (lane >> 4) * 8;

    f32x4 acc[2][4];
#pragma unroll
    for (int m = 0; m < 2; ++m)
#pragma unroll
        for (int n = 0; n < 4; ++n) acc[m][n] = (f32x4){0.f, 0.f, 0.f, 0.f};

    const int tr = tid >> 2;
    const int tc = (tid & 3) << 4;

    for (int kt = 0; kt < DIM / 64; ++kt) {
        const int k0 = kt * 64;
        float4 ra[4], rb[2][4];
        {
            const float4* ga = (const float4*)(X + (size_t)(bm + tr) * DIM + k0 + tc);
#pragma unroll
            for (int q = 0; q < 4; ++q) ra[q] = ga[q];
#pragma unroll
            for (int h = 0; h < 2; ++h) {
                const float4* gw = (const float4*)(W + (size_t)(bn + h * 64 + tr) * DIM + k0 + tc);
#pragma unroll
                for (int q = 0; q < 4; ++q) rb[h][q] = gw[q];
            }
        }
        __syncthreads();
        *(short8*)&As[tr * LDT + tc]     = pack8(ra[0], ra[1]);
        *(short8*)&As[tr * LDT + tc + 8] = pack8(ra[2], ra[3]);
#pragma unroll
        for (int h = 0; h < 2; ++h) {
            *(short8*)&Bs[(h * 64 + tr) * LDT + tc]     = pack8(rb[h][0], rb[h][1]);
            *(short8*)&Bs[(h * 64 + tr) * LDT + tc + 8] = pack8(rb[h][2], rb[h][3]);
        }
        __syncthreads();
#pragma unroll
        for (int kk = 0; kk < 64; kk += 32) {
            short8 af[2], bf[4];
#pragma unroll
            for (int m = 0; m < 2; ++m)
                af[m] = *(const short8*)&As[(wr + m * 16 + fr) * LDT + kk + ke];
#pragma unroll
            for (int n = 0; n < 4; ++n)
                bf[n] = *(const short8*)&Bs[(wc + n * 16 + fr) * LDT + kk + ke];
#pragma unroll
            for (int m = 0; m < 2; ++m)
#pragma unroll
                for (int n = 0; n < 4; ++n)
                    acc[m][n] = __builtin_amdgcn_mfma_f32_16x16x32_bf16(
                        __builtin_bit_cast(bf16x8, af[m]),
                        __builtin_bit_cast(bf16x8, bf[n]),
                        acc[m][n], 0, 0, 0);
        }
    }
#pragma unroll
    for (int n = 0; n < 4; ++n) {
        const int col = bn + wc + n * 16 + fr;
        const float bv = bias[col];
#pragma unroll
        for (int m = 0; m < 2; ++m) {
            const int rbase = bm + wr + m * 16 + (lane >> 4) * 4;
#pragma unroll
            for (int r = 0; r < 4; ++r)
                out[(size_t)(rbase + r) * DIM + col] = acc[m][n][r] + bv;
        }
    }
}

// ---------------------------------------------------------------------------
// 3) walk kernel: 4 waves / row-pair, level-parallel + serial-tail elision
// ---------------------------------------------------------------------------
__global__ __launch_bounds__(256) void kwalk(const float* __restrict__ X, const float* __restrict__ vec,
                                             const uint4* __restrict__ recs, const int* __restrict__ nlvls,
                                             const unsigned* __restrict__ lvmeta_g,
                                             const float* __restrict__ parts, int nparts,
                                             float* __restrict__ out) {
    __shared__ float2 rw[DIM + 2];
    __shared__ unsigned lvm[MAXR];
    const int tid  = threadIdx.x;
    const int wv   = tid >> 6;
    const int lane = tid & 63;
    const int pr   = blockIdx.x;
    const int rA   = pr * 2, rB = pr * 2 + 1;

    {
        const float4* xa = (const float4*)(X + (size_t)rA * DIM);
        const float4* xb = (const float4*)(X + (size_t)rB * DIM);
        for (int c4 = tid; c4 < DIM / 4; c4 += 256) {
            const float4 a = xa[c4], b = xb[c4];
            rw[c4 * 4 + 0] = make_float2(a.x, b.x);
            rw[c4 * 4 + 1] = make_float2(a.y, b.y);
            rw[c4 * 4 + 2] = make_float2(a.z, b.z);
            rw[c4 * 4 + 3] = make_float2(a.w, b.w);
        }
        if (tid < 2) rw[DIM + tid] = make_float2(0.f, 0.f);
    }

    for (int slot = 0; slot < NSLOT; ++slot) {
        if (slot == NW2) {      // between walks: yp = vec * yp
            __syncthreads();
            const float4* v4 = (const float4*)vec;
            for (int c4 = tid; c4 < DIM / 4; c4 += 256) {
                const float4 v = v4[c4];
#pragma unroll
                for (int q = 0; q < 4; ++q) {
                    float2 tv = rw[c4 * 4 + q];
                    const float sc = (q == 0) ? v.x : (q == 1) ? v.y : (q == 2) ? v.z : v.w;
                    tv.x *= sc; tv.y *= sc;
                    rw[c4 * 4 + q] = tv;
                }
            }
        }
        if (tid < MAXR) lvm[tid] = lvmeta_g[slot * MAXR + tid];
        const int nlvl = nlvls[slot];
        __syncthreads();

        const uint4* wbase = recs + (size_t)slot * SLOTREC + (size_t)wv * (PWC * CHUNK);
        // 3-deep record ring over this wave's contiguous stream
        uint4 r0A = wbase[lane],       r0B = wbase[64 + lane];
        uint4 r1A = wbase[128 + lane], r1B = wbase[192 + lane];
        uint4 r2A = wbase[256 + lane], r2B = wbase[320 + lane];
        int t = 0;

        for (int lvl = 0; lvl < nlvl; ++lvl) {
            const unsigned mm = lvm[lvl];
            int n = (int)((mm >> (wv * 8)) & 0xFFu);
            if (wv == 3) n &= 0x7F;
            for (int it = 0; it < n; ++it) {
                int kc = t + 3; if (kc > PWC - 1) kc = PWC - 1;
                const uint4 mA = wbase[(size_t)kc * CHUNK + lane];
                const uint4 mB = wbase[(size_t)kc * CHUNK + 64 + lane];

                const int   ia = (int)r0A.x, ja = (int)r0A.w;
                const int   ib = (int)r0B.x, jb = (int)r0B.w;
                const float ca = bitf(r0A.y), sa = bitf(r0A.z);
                const float cb = bitf(r0B.y), sb = bitf(r0B.z);
                const float2 gai = ldrw(rw, ia), gaj = ldrw(rw, ja);
                const float2 gbi = ldrw(rw, ib), gbj = ldrw(rw, jb);

                float2 wia, wja, wib, wjb;
                wia.x = fmaf(ca, gai.x,  sa * gaj.x);
                wia.y = fmaf(ca, gai.y,  sa * gaj.y);
                wja.x = fmaf(ca, gaj.x, -sa * gai.x);
                wja.y = fmaf(ca, gaj.y, -sa * gai.y);
                wib.x = fmaf(cb, gbi.x,  sb * gbj.x);
                wib.y = fmaf(cb, gbi.y,  sb * gbj.y);
                wjb.x = fmaf(cb, gbj.x, -sb * gbi.x);
                wjb.y = fmaf(cb, gbj.y, -sb * gbi.y);
                strw(rw, ia, wia); strw(rw, ja, wja);
                strw(rw, ib, wib); strw(rw, jb, wjb);

                r0A = r1A; r0B = r1B;
                r1A = r2A; r1B = r2B;
                r2A = mA;  r2B = mB;
                ++t;
            }
            // inter-level barrier, elided inside serial runs (flag bit31)
            if (!(mm & 0x80000000u)) {
                __builtin_amdgcn_sched_barrier(0);
                asm volatile("s_waitcnt lgkmcnt(0)" ::: "memory");
                __builtin_amdgcn_s_barrier();
                __builtin_amdgcn_sched_barrier(0);
            }
        }
    }

    float4* oa = (float4*)(out + (size_t)rA * DIM);
    float4* ob = (float4*)(out + (size_t)rB * DIM);
    const size_t PS = (size_t)ROWS * DIM / 4;
    const float4* qa = (const float4*)parts + (size_t)rA * (DIM / 4);
    const float4* qb = (const float4*)parts + (size_t)rB * (DIM / 4);
    for (int c4 = tid; c4 < DIM / 4; c4 += 256) {
        const float2 p0 = rw[c4 * 4 + 0], p1 = rw[c4 * 4 + 1];
        const float2 p2 = rw[c4 * 4 + 2], p3 = rw[c4 * 4 + 3];
        float4 ta = oa[c4], tb = ob[c4];
        for (int p = 0; p < nparts; ++p) {
            const float4 a = qa[c4 + (size_t)p * PS];
            const float4 b = qb[c4 + (size_t)p * PS];
            ta.x += a.x; ta.y += a.y; ta.z += a.z; ta.w += a.w;
            tb.x += b.x; tb.y += b.y; tb.z += b.z; tb.w += b.w;
        }
        ta.x += p0.x; ta.y += p1.x; ta.z += p2.x; ta.w += p3.x;
        tb.x += p0.y; tb.y += p1.y; tb.z += p2.y; tb.w += p3.y;
        oa[c4] = ta; ob[c4] = tb;
    }
}

// ---------------------------------------------------------------------------
extern "C" void kernel_launch(void* const* d_in, const int* in_sizes, int n_in,
                              void* d_out, int out_size, void* d_ws, size_t ws_size,
                              hipStream_t stream) {
    const float* X    = (const float*)d_in[0];
    const float* W    = (const float*)d_in[1];
    const float* bias = (const float*)d_in[2];
    const float* vec  = (const float*)d_in[3];
    const int*   i1   = (const int*)d_in[4];
    const int*   j1   = (const int*)d_in[5];
    const float* c1   = (const float*)d_in[6];
    const float* s1   = (const float*)d_in[7];
    const int*   i2   = (const int*)d_in[8];
    const int*   j2   = (const int*)d_in[9];
    const float* c2   = (const float*)d_in[10];
    const float* s2   = (const float*)d_in[11];
    float* out = (float*)d_out;

    const size_t RD         = (size_t)ROWS * DIM * 4;            // 8 MiB
    const size_t WBB        = (size_t)DIM * DIM * 2;             // 32 MiB
    const size_t XBB        = (size_t)ROWS * DIM * 2;            // 4 MiB
    const size_t recs_bytes = (size_t)NSLOT * SLOTREC * 16;      // 9.44 MiB
    const size_t off_lvm    = recs_bytes + 1024;
    const size_t off_parts  = recs_bytes + 16384;

    // tiered Ksplit by workspace size
    int nks = 0;
    size_t off_wb = 0;
    {
        const size_t need4 = off_parts + 3 * RD + WBB + XBB;
        const size_t need2 = off_parts + 1 * RD + WBB + XBB;
        if      (ws_size >= need4) { nks = 4; off_wb = off_parts + 3 * RD; }
        else if (ws_size >= need2) { nks = 2; off_wb = off_parts + 1 * RD; }
    }

    uint4*    recs   = (uint4*)d_ws;
    int*      nlvlsb = (int*)((char*)d_ws + recs_bytes);
    unsigned* lvmeta = (unsigned*)((char*)d_ws + off_lvm);
    float*    parts  = (float*)((char*)d_ws + off_parts);
    short*    wbuf   = (short*)((char*)d_ws + off_wb);
    short*    xbuf   = (short*)((char*)d_ws + off_wb + WBB);
    const bool bf = (nks > 0);

    hipLaunchKernelGGL(kfused, dim3(NSLOT + (bf ? (NCVW + NCVX) : 0)), dim3(KT), 0, stream,
                       i1, j1, c1, s1, i2, j2, c2, s2, recs, nlvlsb, lvmeta,
                       bf ? 1 : 0, W, X, wbuf, xbuf);
    if (bf)
        hipLaunchKernelGGL(kgemm_bf, dim3(128 * nks), dim3(256), 0, stream,
                           xbuf, wbuf, bias, out, parts, nks);
    else
        hipLaunchKernelGGL(kgemm_small, dim3(256), dim3(256), 0, stream, X, W, bias, out);
    hipLaunchKernelGGL(kwalk, dim3(ROWS / 2), dim3(256), 0, stream,
                       X, vec, recs, nlvlsb, lvmeta, parts, bf ? (nks - 1) : 0, out);
}

// Round 17
// 213.347 us; speedup vs baseline: 1.5790x; 1.0607x over previous
//
#include <hip/hip_runtime.h>

// KacLayer: out[512][4096] = x @ W^T + b  +  Kac2( vec * Kac1( x ) )
//
//  kfused: blocks 0..11: per-8192-step window scheduler (R16 structure:
//          depth election; per-wave chunk streams; levels <=2 chunks run
//          serial on wave0 with barrier elision between consecutive serial
//          levels). Records -> global (pad-prefilled). Bit-exact reorder.
//          blocks 12..1163: fp32->bf16 convert of W and X into d_ws.
//  kboth : ONE launch, blocks 0..255 = walk path (4 waves / row-pair,
//          level-parallel, light barriers, writes walkbuf), blocks 256..
//          256+128*nks-1 = GEMM path (128x128 tile, BK=64, global_load_lds
//          staging, swizzled LDS, Ksplit). Walk is latency-bound (no MFMA),
//          GEMM is MFMA-bound -> co-resident blocks overlap (m114).
//  kadd  : out = gemm_out + walkbuf + sum(parts).

#define DIM    4096
#define ROWS   512
#define NSTEPS 49152
#define WSTEPS 8192
#define NW2    (NSTEPS / WSTEPS)   // 6 windows per walk
#define NSLOT  (2 * NW2)           // 12 slots
#define NSG    16                  // rank subgroups (one per ksched wave)
#define CHUNK  128
#define WVN    4                   // walk waves per block
#define PWC    96                  // per-wave chunk capacity per slot
#define SLOTREC (WVN * PWC * CHUNK)   // 49152 records per slot
#define MAXR   96
#define PADI   4096
#define PADJ   4097
#define KT     1024                // scheduler threads
#define SPT    (WSTEPS / KT)       // 8 steps per thread
#define NCVW   1024                // W-convert blocks
#define NCVX   128                 // X-convert blocks
#define SMEMB  33664               // kboth shared bytes (walk needs 33168)

typedef short  short8 __attribute__((ext_vector_type(8)));
typedef __bf16 bf16x8 __attribute__((ext_vector_type(8)));
typedef float  f32x4  __attribute__((ext_vector_type(4)));

__device__ inline short f2bf(float f) {
    unsigned u = __builtin_bit_cast(unsigned, f);
    u += 0x7FFFu + ((u >> 16) & 1u);
    return (short)(u >> 16);
}
__device__ inline short8 pack8(float4 a, float4 b) {
    short8 r;
    r[0] = f2bf(a.x); r[1] = f2bf(a.y); r[2] = f2bf(a.z); r[3] = f2bf(a.w);
    r[4] = f2bf(b.x); r[5] = f2bf(b.y); r[6] = f2bf(b.z); r[7] = f2bf(b.w);
    return r;
}
__device__ inline float bitf(unsigned u) { return __builtin_bit_cast(float, u); }
__device__ inline float2 ldrw(const float2* rw, int boff) {
    return *(const float2*)((const char*)rw + boff);
}
__device__ inline void strw(float2* rw, int boff, float2 v) {
    *(float2*)((char*)rw + boff) = v;
}
__device__ inline void gl16(const short* g, short* l) {
    __builtin_amdgcn_global_load_lds((const __attribute__((address_space(1))) unsigned*)g,
                                     (__attribute__((address_space(3))) unsigned*)l, 16, 0, 0);
}

// ---------------------------------------------------------------------------
// 1) fused scheduler (blocks 0..NSLOT-1) + bf16 convert (blocks NSLOT..)
// ---------------------------------------------------------------------------
__global__ __launch_bounds__(KT) void kfused(
    const int* __restrict__ i1, const int* __restrict__ j1,
    const float* __restrict__ c1, const float* __restrict__ s1,
    const int* __restrict__ i2, const int* __restrict__ j2,
    const float* __restrict__ c2, const float* __restrict__ s2,
    uint4* __restrict__ recs, int* __restrict__ nlvls, unsigned* __restrict__ lvmeta_g,
    int doconv, const float* __restrict__ W, const float* __restrict__ X,
    short* __restrict__ wb, short* __restrict__ xb) {

    if (blockIdx.x >= NSLOT) {
        if (!doconv) return;
        const int cb = blockIdx.x - NSLOT;
        const float* src; short* dst; size_t base;
        if (cb < NCVW) { src = W; dst = wb; base = (size_t)cb * 16384; }
        else           { src = X; dst = xb; base = (size_t)(cb - NCVW) * 16384; }
        const size_t o = base + (size_t)threadIdx.x * 16;
        const float4* s4 = (const float4*)(src + o);
        const float4 a0 = s4[0], a1 = s4[1], a2 = s4[2], a3 = s4[3];
        *(short8*)(dst + o)     = pack8(a0, a1);
        *(short8*)(dst + o + 8) = pack8(a2, a3);
        return;
    }

    __shared__ unsigned tbl[DIM];
    __shared__ unsigned spair[WSTEPS];
    __shared__ unsigned lvrk[WSTEPS];
    __shared__ int lcnt[MAXR * NSG];
    __shared__ unsigned lvpk[MAXR], wvbase[MAXR];
    __shared__ unsigned char serf[MAXR];
    __shared__ int nlvlsh;

    const int b    = blockIdx.x;
    const int walk = b / NW2;
    const int w    = b % NW2;
    const int t    = threadIdx.x;
    const int gb   = w * WSTEPS;
    const int sg   = t >> 6;

    const int*   I = walk ? i2 : i1;
    const int*   J = walk ? j2 : j1;
    const float* C = walk ? c2 : c1;
    const float* S = walk ? s2 : s1;

    uint4* slotp = recs + (size_t)b * SLOTREC;
    {
        const uint4 padrec = { (unsigned)(PADI * 8), 0x3F800000u, 0u, (unsigned)(PADJ * 8) };
        for (int k = t; k < SLOTREC; k += KT) slotp[k] = padrec;
    }
    for (int s = t; s < WSTEPS; s += KT)
        spair[s] = (unsigned)I[gb + s] | ((unsigned)J[gb + s] << 16);
    for (int k = t; k < DIM; k += KT) tbl[k] = 0xFFFFFFFFu;
    for (int k = t; k < MAXR * NSG; k += KT) lcnt[k] = 0;
    if (t < MAXR) serf[t] = 0;
    if (t == 0) nlvlsh = 1;
    __syncthreads();

    unsigned pmask = (1u << SPT) - 1u;
    for (int rr = 0; rr < MAXR; ++rr) {
        const unsigned rk = (unsigned)(MAXR - 1 - rr) << 13;
#pragma unroll
        for (int q = 0; q < SPT; ++q)
            if (pmask & (1u << q)) {
                const int s = q * KT + t;
                const unsigned sp = spair[s];
                const unsigned key = rk | (unsigned)s;
                atomicMin(&tbl[sp & 0xFFFFu], key);
                atomicMin(&tbl[sp >> 16], key);
            }
        __syncthreads();
#pragma unroll
        for (int q = 0; q < SPT; ++q)
            if (pmask & (1u << q)) {
                const int s = q * KT + t;
                const unsigned sp = spair[s];
                const unsigned key = rk | (unsigned)s;
                if (tbl[sp & 0xFFFFu] == key && tbl[sp >> 16] == key) {
                    const int rank = atomicAdd(&lcnt[rr * NSG + sg], 1);
                    lvrk[s] = ((unsigned)rank << 8) | (unsigned)rr;
                    pmask &= ~(1u << q);
                }
            }
        const int np = __syncthreads_count(pmask != 0);
        if (np == 0) break;
    }
#pragma unroll
    for (int q = 0; q < SPT; ++q)
        if (pmask & (1u << q)) {
            const int s = q * KT + t;
            const int rank = atomicAdd(&lcnt[(MAXR - 1) * NSG + sg], 1);
            lvrk[s] = ((unsigned)rank << 8) | (unsigned)(MAXR - 1);
        }
    __syncthreads();

    if (t < MAXR) {
        int run = 0;
        for (int g = 0; g < NSG; ++g) {
            const int v = lcnt[t * NSG + g];
            lcnt[t * NSG + g] = run;
            run += v;
        }
        const int nch = (run + 127) >> 7;
        unsigned pk = 0;
        if (run > 0 && nch <= 2) { serf[t] = 1; pk = (unsigned)nch; }
        else {
#pragma unroll
            for (int wv = 0; wv < WVN; ++wv)
                pk |= (unsigned)((nch + (WVN - 1 - wv)) >> 2) << (8 * wv);
        }
        lvpk[t] = pk;
        if (run > 0) atomicMax(&nlvlsh, t + 1);
    }
    __syncthreads();
    if (t < 64) {
        const int l = t;
        const unsigned w1 = lvpk[l];
        unsigned x1 = w1;
        for (int off = 1; off < 64; off <<= 1) {
            const unsigned v = (unsigned)__shfl_up((int)x1, off);
            if (l >= off) x1 += v;
        }
        wvbase[l] = x1 - w1;
        const unsigned seg1 = (unsigned)__shfl((int)x1, 63);
        const int l2 = 64 + (l & 31);
        const unsigned w2 = lvpk[l2];
        unsigned x2 = w2;
        for (int off = 1; off < 32; off <<= 1) {
            const unsigned v = (unsigned)__shfl_up((int)x2, off);
            if ((l & 31) >= off) x2 += v;
        }
        if (l < 32) wvbase[l2] = seg1 + x2 - w2;
    }
    __syncthreads();
    if (t < MAXR - 1) {
        if (serf[t] && serf[t + 1]) lvpk[t] |= 0x80000000u;
    }
    __syncthreads();
    if (t == 0) nlvls[b] = nlvlsh;
    if (t < MAXR) lvmeta_g[b * MAXR + t] = lvpk[t];

#pragma unroll
    for (int q = 0; q < SPT; ++q) {
        const int s = q * KT + t;
        const unsigned v = lvrk[s];
        const int lvl  = (int)(v & 0xFFu);
        const int rank = (int)(v >> 8) + lcnt[lvl * NSG + sg];
        const int cl   = rank >> 7;
        const int pos  = rank & 127;
        int wv2, wc2;
        if (serf[lvl]) { wv2 = 0; wc2 = cl; }
        else           { wv2 = cl & (WVN - 1); wc2 = cl >> 2; }
        const int pch = (int)((wvbase[lvl] >> (8 * wv2)) & 0xFFu) + wc2;
        if (pch < PWC) {
            const unsigned sp = spair[s];
            const int g = gb + s;
            uint4 r;
            r.x = (sp & 0xFFFFu) * 8u;
            r.y = __builtin_bit_cast(unsigned, C[g]);
            r.z = __builtin_bit_cast(unsigned, S[g]);
            r.w = (sp >> 16) * 8u;
            slotp[((size_t)wv2 * PWC + pch) * CHUNK + pos] = r;
        }
    }
}

// ---------------------------------------------------------------------------
// walk body (shared by kboth path and fallback kernel)
// ---------------------------------------------------------------------------
__device__ void walk_body(char* smem, int pr,
                          const float* __restrict__ X, const float* __restrict__ vec,
                          const uint4* __restrict__ recs, const int* __restrict__ nlvls,
                          const unsigned* __restrict__ lvmeta_g,
                          float* __restrict__ dstbuf, int directadd) {
    float2* rw = (float2*)smem;
    unsigned* lvm = (unsigned*)(smem + (DIM + 2) * 8);
    const int tid  = threadIdx.x;
    const int wv   = tid >> 6;
    const int lane = tid & 63;
    const int rA   = pr * 2, rB = pr * 2 + 1;

    {
        const float4* xa = (const float4*)(X + (size_t)rA * DIM);
        const float4* xb = (const float4*)(X + (size_t)rB * DIM);
        for (int c4 = tid; c4 < DIM / 4; c4 += 256) {
            const float4 a = xa[c4], b = xb[c4];
            rw[c4 * 4 + 0] = make_float2(a.x, b.x);
            rw[c4 * 4 + 1] = make_float2(a.y, b.y);
            rw[c4 * 4 + 2] = make_float2(a.z, b.z);
            rw[c4 * 4 + 3] = make_float2(a.w, b.w);
        }
        if (tid < 2) rw[DIM + tid] = make_float2(0.f, 0.f);
    }

    for (int slot = 0; slot < NSLOT; ++slot) {
        if (slot == NW2) {
            __syncthreads();
            const float4* v4 = (const float4*)vec;
            for (int c4 = tid; c4 < DIM / 4; c4 += 256) {
                const float4 v = v4[c4];
#pragma unroll
                for (int q = 0; q < 4; ++q) {
                    float2 tv = rw[c4 * 4 + q];
                    const float sc = (q == 0) ? v.x : (q == 1) ? v.y : (q == 2) ? v.z : v.w;
                    tv.x *= sc; tv.y *= sc;
                    rw[c4 * 4 + q] = tv;
                }
            }
        }
        if (tid < MAXR) lvm[tid] = lvmeta_g[slot * MAXR + tid];
        const int nlvl = nlvls[slot];
        __syncthreads();

        const uint4* wbase = recs + (size_t)slot * SLOTREC + (size_t)wv * (PWC * CHUNK);
        uint4 r0A = wbase[lane],       r0B = wbase[64 + lane];
        uint4 r1A = wbase[128 + lane], r1B = wbase[192 + lane];
        uint4 r2A = wbase[256 + lane], r2B = wbase[320 + lane];
        int t = 0;

        for (int lvl = 0; lvl < nlvl; ++lvl) {
            const unsigned mm = lvm[lvl];
            int n = (int)((mm >> (wv * 8)) & 0xFFu);
            if (wv == 3) n &= 0x7F;
            for (int it = 0; it < n; ++it) {
                int kc = t + 3; if (kc > PWC - 1) kc = PWC - 1;
                const uint4 mA = wbase[(size_t)kc * CHUNK + lane];
                const uint4 mB = wbase[(size_t)kc * CHUNK + 64 + lane];

                const int   ia = (int)r0A.x, ja = (int)r0A.w;
                const int   ib = (int)r0B.x, jb = (int)r0B.w;
                const float ca = bitf(r0A.y), sa = bitf(r0A.z);
                const float cb = bitf(r0B.y), sb = bitf(r0B.z);
                const float2 gai = ldrw(rw, ia), gaj = ldrw(rw, ja);
                const float2 gbi = ldrw(rw, ib), gbj = ldrw(rw, jb);

                float2 wia, wja, wib, wjb;
                wia.x = fmaf(ca, gai.x,  sa * gaj.x);
                wia.y = fmaf(ca, gai.y,  sa * gaj.y);
                wja.x = fmaf(ca, gaj.x, -sa * gai.x);
                wja.y = fmaf(ca, gaj.y, -sa * gai.y);
                wib.x = fmaf(cb, gbi.x,  sb * gbj.x);
                wib.y = fmaf(cb, gbi.y,  sb * gbj.y);
                wjb.x = fmaf(cb, gbj.x, -sb * gbi.x);
                wjb.y = fmaf(cb, gbj.y, -sb * gbi.y);
                strw(rw, ia, wia); strw(rw, ja, wja);
                strw(rw, ib, wib); strw(rw, jb, wjb);

                r0A = r1A; r0B = r1B;
                r1A = r2A; r1B = r2B;
                r2A = mA;  r2B = mB;
                ++t;
            }
            if (!(mm & 0x80000000u)) {
                __builtin_amdgcn_sched_barrier(0);
                asm volatile("s_waitcnt lgkmcnt(0)" ::: "memory");
                __builtin_amdgcn_s_barrier();
                __builtin_amdgcn_sched_barrier(0);
            }
        }
    }

    float4* oa = (float4*)(dstbuf + (size_t)rA * DIM);
    float4* ob = (float4*)(dstbuf + (size_t)rB * DIM);
    for (int c4 = tid; c4 < DIM / 4; c4 += 256) {
        const float2 p0 = rw[c4 * 4 + 0], p1 = rw[c4 * 4 + 1];
        const float2 p2 = rw[c4 * 4 + 2], p3 = rw[c4 * 4 + 3];
        float4 ta, tb;
        if (directadd) { ta = oa[c4]; tb = ob[c4]; }
        else           { ta = (float4){0,0,0,0}; tb = (float4){0,0,0,0}; }
        ta.x += p0.x; ta.y += p1.x; ta.z += p2.x; ta.w += p3.x;
        tb.x += p0.y; tb.y += p1.y; tb.z += p2.y; tb.w += p3.y;
        oa[c4] = ta; ob[c4] = tb;
    }
}

// ---------------------------------------------------------------------------
// GEMM body (bf16, global_load_lds staging, BK=64)
// ---------------------------------------------------------------------------
__device__ void gemm_body(char* smem, int bid,
                          const short* __restrict__ Xb, const short* __restrict__ Wb,
                          const float* __restrict__ bias, float* __restrict__ out,
                          float* __restrict__ parts, int nks) {
    short* As = (short*)smem;
    short* Bs = As + 128 * 64;
    const int ks   = bid % nks;
    const int tile = bid / nks;
    const int bm   = (tile >> 5) * 128;
    const int bn   = (tile & 31) * 128;
    const int tid  = threadIdx.x;
    const int lane = tid & 63;
    const int wv   = tid >> 6;
    const int wr   = (wv >> 1) * 64;
    const int wc   = (wv & 1) * 64;
    const int fr   = lane & 15;
    const int ke   = (lane >> 4) * 8;

    f32x4 acc[4][4];
#pragma unroll
    for (int m = 0; m < 4; ++m)
#pragma unroll
        for (int n = 0; n < 4; ++n) acc[m][n] = (f32x4){0.f, 0.f, 0.f, 0.f};

    const int lrow = lane >> 3;
    const int scol = (((lane & 7) ^ (lrow & 7)) << 3);
    const short* gx = Xb + (size_t)(bm + wv * 32 + lrow) * DIM + scol;
    const short* gw = Wb + (size_t)(bn + wv * 32 + lrow) * DIM + scol;
    short* lA = As + wv * 2048;
    short* lB = Bs + wv * 2048;

    const int nkt   = (DIM / 64) / nks;
    const int kbase = ks * (DIM / nks);
    for (int kt = 0; kt < nkt; ++kt) {
        const int k0 = kbase + kt * 64;
        __syncthreads();
#pragma unroll
        for (int q = 0; q < 4; ++q) {
            gl16(gx + (size_t)(q * 8) * DIM + k0, lA + q * 512);
            gl16(gw + (size_t)(q * 8) * DIM + k0, lB + q * 512);
        }
        __syncthreads();
#pragma unroll
        for (int kk = 0; kk < 64; kk += 32) {
            const int sb = (kk + ke) >> 3;
            short8 af[4], bf[4];
#pragma unroll
            for (int m = 0; m < 4; ++m) {
                const int R = wr + m * 16 + fr;
                af[m] = *(const short8*)&As[R * 64 + ((sb ^ (R & 7)) << 3)];
            }
#pragma unroll
            for (int n = 0; n < 4; ++n) {
                const int R = wc + n * 16 + fr;
                bf[n] = *(const short8*)&Bs[R * 64 + ((sb ^ (R & 7)) << 3)];
            }
#pragma unroll
            for (int m = 0; m < 4; ++m)
#pragma unroll
                for (int n = 0; n < 4; ++n)
                    acc[m][n] = __builtin_amdgcn_mfma_f32_16x16x32_bf16(
                        __builtin_bit_cast(bf16x8, af[m]),
                        __builtin_bit_cast(bf16x8, bf[n]),
                        acc[m][n], 0, 0, 0);
        }
    }
    float* dst = ks ? (parts + (size_t)(ks - 1) * ROWS * DIM) : out;
#pragma unroll
    for (int n = 0; n < 4; ++n) {
        const int col = bn + wc + n * 16 + fr;
        const float bv = ks ? 0.f : bias[col];
#pragma unroll
        for (int m = 0; m < 4; ++m) {
            const int rbase = bm + wr + m * 16 + (lane >> 4) * 4;
#pragma unroll
            for (int r = 0; r < 4; ++r)
                dst[(size_t)(rbase + r) * DIM + col] = acc[m][n][r] + bv;
        }
    }
}

// ---------------------------------------------------------------------------
// 2) kboth: walk (blocks 0..255) + GEMM (blocks 256..) in one launch
// ---------------------------------------------------------------------------
__global__ __launch_bounds__(256) void kboth(
    const float* __restrict__ X, const float* __restrict__ vec,
    const uint4* __restrict__ recs, const int* __restrict__ nlvls,
    const unsigned* __restrict__ lvmeta_g, float* __restrict__ walkbuf,
    const short* __restrict__ Xb, const short* __restrict__ Wb,
    const float* __restrict__ bias, float* __restrict__ out,
    float* __restrict__ parts, int nks) {
    __shared__ __align__(16) char smem[SMEMB];
    if (blockIdx.x < ROWS / 2)
        walk_body(smem, blockIdx.x, X, vec, recs, nlvls, lvmeta_g, walkbuf, 0);
    else
        gemm_body(smem, blockIdx.x - ROWS / 2, Xb, Wb, bias, out, parts, nks);
}

// ---------------------------------------------------------------------------
// 3) kadd: out += walkbuf + sum(parts)
// ---------------------------------------------------------------------------
__global__ __launch_bounds__(256) void kadd(float* __restrict__ out,
                                            const float* __restrict__ walkbuf,
                                            const float* __restrict__ parts, int nparts) {
    const size_t N = (size_t)ROWS * DIM / 4;
    const size_t i0 = (size_t)blockIdx.x * 256 + threadIdx.x;
    float4* o4 = (float4*)out;
    const float4* w4 = (const float4*)walkbuf;
    const float4* p4 = (const float4*)parts;
    for (size_t i = i0; i < N; i += (size_t)gridDim.x * 256) {
        float4 t = o4[i];
        const float4 s = w4[i];
        t.x += s.x; t.y += s.y; t.z += s.z; t.w += s.w;
        for (int p = 0; p < nparts; ++p) {
            const float4 a = p4[i + (size_t)p * N];
            t.x += a.x; t.y += a.y; t.z += a.z; t.w += a.w;
        }
        o4[i] = t;
    }
}

// ---------------------------------------------------------------------------
// fallback kernels (small workspace): fp32-staging GEMM + direct-add walk
// ---------------------------------------------------------------------------
#define LDT 72
__global__ __launch_bounds__(256) void kgemm_small(const float* __restrict__ X, const float* __restrict__ W,
                                                   const float* __restrict__ bias, float* __restrict__ out) {
    __shared__ short As[64 * LDT];
    __shared__ short Bs[128 * LDT];
    const int tid  = threadIdx.x;
    const int bn   = (blockIdx.x & 31) * 128;
    const int bm   = (blockIdx.x >> 5) * 64;
    const int lane = tid & 63;
    const int wv   = tid >> 6;
    const int wr   = (wv >> 1) * 32;
    const int wc   = (wv & 1) * 64;
    const int fr   = lane & 15;
    const int ke   = (lane >> 4) * 8;

    f32x4 acc[2][4];
#pragma unroll
    for (int m = 0; m < 2; ++m)
#pragma unroll
        for (int n = 0; n < 4; ++n) acc[m][n] = (f32x4){0.f, 0.f, 0.f, 0.f};

    const int tr = tid >> 2;
    const int tc = (tid & 3) << 4;

    for (int kt = 0; kt < DIM / 64; ++kt) {
        const int k0 = kt * 64;
        float4 ra[4], rb[2][4];
        {
            const float4* ga = (const float4*)(X + (size_t)(bm + tr) * DIM + k0 + tc);
#pragma unroll
            for (int q = 0; q < 4; ++q) ra[q] = ga[q];
#pragma unroll
            for (int h = 0; h < 2; ++h) {
                const float4* gw = (const float4*)(W + (size_t)(bn + h * 64 + tr) * DIM + k0 + tc);
#pragma unroll
                for (int q = 0; q < 4; ++q) rb[h][q] = gw[q];
            }
        }
        __syncthreads();
        *(short8*)&As[tr * LDT + tc]     = pack8(ra[0], ra[1]);
        *(short8*)&As[tr * LDT + tc + 8] = pack8(ra[2], ra[3]);
#pragma unroll
        for (int h = 0; h < 2; ++h) {
            *(short8*)&Bs[(h * 64 + tr) * LDT + tc]     = pack8(rb[h][0], rb[h][1]);
            *(short8*)&Bs[(h * 64 + tr) * LDT + tc + 8] = pack8(rb[h][2], rb[h][3]);
        }
        __syncthreads();
#pragma unroll
        for (int kk = 0; kk < 64; kk += 32) {
            short8 af[2], bf[4];
#pragma unroll
            for (int m = 0; m < 2; ++m)
                af[m] = *(const short8*)&As[(wr + m * 16 + fr) * LDT + kk + ke];
#pragma unroll
            for (int n = 0; n < 4; ++n)
                bf[n] = *(const short8*)&Bs[(wc + n * 16 + fr) * LDT + kk + ke];
#pragma unroll
            for (int m = 0; m < 2; ++m)
#pragma unroll
                for (int n = 0; n < 4; ++n)
                    acc[m][n] = __builtin_amdgcn_mfma_f32_16x16x32_bf16(
                        __builtin_bit_cast(bf16x8, af[m]),
                        __builtin_bit_cast(bf16x8, bf[n]),
                        acc[m][n], 0, 0, 0);
        }
    }
#pragma unroll
    for (int n = 0; n < 4; ++n) {
        const int col = bn + wc + n * 16 + fr;
        const float bv = bias[col];
#pragma unroll
        for (int m = 0; m < 2; ++m) {
            const int rbase = bm + wr + m * 16 + (lane >> 4) * 4;
#pragma unroll
            for (int r = 0; r < 4; ++r)
                out[(size_t)(rbase + r) * DIM + col] = acc[m][n][r] + bv;
        }
    }
}

__global__ __launch_bounds__(256) void kwalk_fb(const float* __restrict__ X, const float* __restrict__ vec,
                                                const uint4* __restrict__ recs, const int* __restrict__ nlvls,
                                                const unsigned* __restrict__ lvmeta_g,
                                                float* __restrict__ out) {
    __shared__ __align__(16) char smem[SMEMB];
    walk_body(smem, blockIdx.x, X, vec, recs, nlvls, lvmeta_g, out, 1);
}

// ---------------------------------------------------------------------------
extern "C" void kernel_launch(void* const* d_in, const int* in_sizes, int n_in,
                              void* d_out, int out_size, void* d_ws, size_t ws_size,
                              hipStream_t stream) {
    const float* X    = (const float*)d_in[0];
    const float* W    = (const float*)d_in[1];
    const float* bias = (const float*)d_in[2];
    const float* vec  = (const float*)d_in[3];
    const int*   i1   = (const int*)d_in[4];
    const int*   j1   = (const int*)d_in[5];
    const float* c1   = (const float*)d_in[6];
    const float* s1   = (const float*)d_in[7];
    const int*   i2   = (const int*)d_in[8];
    const int*   j2   = (const int*)d_in[9];
    const float* c2   = (const float*)d_in[10];
    const float* s2   = (const float*)d_in[11];
    float* out = (float*)d_out;

    const size_t RD         = (size_t)ROWS * DIM * 4;            // 8 MiB
    const size_t WBB        = (size_t)DIM * DIM * 2;             // 32 MiB
    const size_t XBB        = (size_t)ROWS * DIM * 2;            // 4 MiB
    const size_t recs_bytes = (size_t)NSLOT * SLOTREC * 16;      // 9.44 MiB
    const size_t off_lvm    = recs_bytes + 1024;
    const size_t off_parts  = recs_bytes + 16384;

    int nks = 0;
    size_t off_wb = 0;
    {
        const size_t need4 = off_parts + 3 * RD + WBB + XBB + RD;
        const size_t need2 = off_parts + 1 * RD + WBB + XBB + RD;
        if      (ws_size >= need4) { nks = 4; off_wb = off_parts + 3 * RD; }
        else if (ws_size >= need2) { nks = 2; off_wb = off_parts + 1 * RD; }
    }

    uint4*    recs   = (uint4*)d_ws;
    int*      nlvlsb = (int*)((char*)d_ws + recs_bytes);
    unsigned* lvmeta = (unsigned*)((char*)d_ws + off_lvm);
    float*    parts  = (float*)((char*)d_ws + off_parts);
    short*    wbuf   = (short*)((char*)d_ws + off_wb);
    short*    xbuf   = (short*)((char*)d_ws + off_wb + WBB);
    float*    wkbuf  = (float*)((char*)d_ws + off_wb + WBB + XBB);
    const bool bf = (nks > 0);

    hipLaunchKernelGGL(kfused, dim3(NSLOT + (bf ? (NCVW + NCVX) : 0)), dim3(KT), 0, stream,
                       i1, j1, c1, s1, i2, j2, c2, s2, recs, nlvlsb, lvmeta,
                       bf ? 1 : 0, W, X, wbuf, xbuf);
    if (bf) {
        hipLaunchKernelGGL(kboth, dim3(ROWS / 2 + 128 * nks), dim3(256), 0, stream,
                           X, vec, recs, nlvlsb, lvmeta, wkbuf,
                           xbuf, wbuf, bias, out, parts, nks);
        hipLaunchKernelGGL(kadd, dim3(512), dim3(256), 0, stream,
                           out, wkbuf, parts, nks - 1);
    } else {
        hipLaunchKernelGGL(kgemm_small, dim3(256), dim3(256), 0, stream, X, W, bias, out);
        hipLaunchKernelGGL(kwalk_fb, dim3(ROWS / 2), dim3(256), 0, stream,
                           X, vec, recs, nlvlsb, lvmeta, out);
    }
}

// Round 18
// 205.427 us; speedup vs baseline: 1.6399x; 1.0386x over previous
//
#include <hip/hip_runtime.h>

// KacLayer: out[512][4096] = x @ W^T + b  +  Kac2( vec * Kac1( x ) )
//
//  kfused: blocks 0..11: per-8192-step window scheduler. Depth election ->
//          per-wave chunk streams (levels <=2 chunks serial on wave0, barrier
//          elision flag). EXACT EMISSION: no pad prefill; election LDS is
//          reused as a u16 inverse permutation over used positions, then one
//          coalesced pass writes each used position exactly once (real record
//          or identity pad). Bit-exact reorder of commuting Givens rotations.
//          blocks 12..1163: fp32->bf16 convert of W and X into d_ws.
//  kboth : ONE launch, blocks 0..255 = walk path (4 waves / row-pair,
//          level-parallel, light barriers, writes walkbuf), blocks 256.. =
//          GEMM path (128x128 tile, BK=64, global_load_lds staging, swizzled
//          LDS, Ksplit). Walk latency-bound + GEMM MFMA-bound -> overlap.
//  kadd  : out = gemm_out + walkbuf + sum(parts).

#define DIM    4096
#define ROWS   512
#define NSTEPS 49152
#define WSTEPS 8192
#define NW2    (NSTEPS / WSTEPS)   // 6 windows per walk
#define NSLOT  (2 * NW2)           // 12 slots
#define NSG    16                  // rank subgroups (one per ksched wave)
#define CHUNK  128
#define WVN    4                   // walk waves per block
#define PWC    96                  // per-wave chunk capacity per slot
#define SLOTREC (WVN * PWC * CHUNK)   // 49152 records per slot
#define MAXR   96
#define PADI   4096
#define PADJ   4097
#define KT     1024                // scheduler threads
#define SPT    (WSTEPS / KT)       // 8 steps per thread
#define NCVW   1024                // W-convert blocks
#define NCVX   128                 // X-convert blocks
#define SMEMB  33664               // kboth shared bytes (walk needs 33168)
#define INVCAP ((DIM + WSTEPS) * 2)   // 24576 u16 entries = 192 chunks

typedef short  short8 __attribute__((ext_vector_type(8)));
typedef __bf16 bf16x8 __attribute__((ext_vector_type(8)));
typedef float  f32x4  __attribute__((ext_vector_type(4)));

__device__ inline short f2bf(float f) {
    unsigned u = __builtin_bit_cast(unsigned, f);
    u += 0x7FFFu + ((u >> 16) & 1u);
    return (short)(u >> 16);
}
__device__ inline short8 pack8(float4 a, float4 b) {
    short8 r;
    r[0] = f2bf(a.x); r[1] = f2bf(a.y); r[2] = f2bf(a.z); r[3] = f2bf(a.w);
    r[4] = f2bf(b.x); r[5] = f2bf(b.y); r[6] = f2bf(b.z); r[7] = f2bf(b.w);
    return r;
}
__device__ inline float bitf(unsigned u) { return __builtin_bit_cast(float, u); }
__device__ inline float2 ldrw(const float2* rw, int boff) {
    return *(const float2*)((const char*)rw + boff);
}
__device__ inline void strw(float2* rw, int boff, float2 v) {
    *(float2*)((char*)rw + boff) = v;
}
__device__ inline void gl16(const short* g, short* l) {
    __builtin_amdgcn_global_load_lds((const __attribute__((address_space(1))) unsigned*)g,
                                     (__attribute__((address_space(3))) unsigned*)l, 16, 0, 0);
}

// ---------------------------------------------------------------------------
// 1) fused scheduler (blocks 0..NSLOT-1) + bf16 convert (blocks NSLOT..)
// ---------------------------------------------------------------------------
__global__ __launch_bounds__(KT) void kfused(
    const int* __restrict__ i1, const int* __restrict__ j1,
    const float* __restrict__ c1, const float* __restrict__ s1,
    const int* __restrict__ i2, const int* __restrict__ j2,
    const float* __restrict__ c2, const float* __restrict__ s2,
    uint4* __restrict__ recs, int* __restrict__ nlvls, unsigned* __restrict__ lvmeta_g,
    int doconv, const float* __restrict__ W, const float* __restrict__ X,
    short* __restrict__ wb, short* __restrict__ xb) {

    if (blockIdx.x >= NSLOT) {
        if (!doconv) return;
        const int cb = blockIdx.x - NSLOT;
        const float* src; short* dst; size_t base;
        if (cb < NCVW) { src = W; dst = wb; base = (size_t)cb * 16384; }
        else           { src = X; dst = xb; base = (size_t)(cb - NCVW) * 16384; }
        const size_t o = base + (size_t)threadIdx.x * 16;
        const float4* s4 = (const float4*)(src + o);
        const float4 a0 = s4[0], a1 = s4[1], a2 = s4[2], a3 = s4[3];
        *(short8*)(dst + o)     = pack8(a0, a1);
        *(short8*)(dst + o + 8) = pack8(a2, a3);
        return;
    }

    // pool: election tbl[DIM] + spair[WSTEPS]; reused as u16 inv after layout
    __shared__ unsigned pool[DIM + WSTEPS];      // 48 KB
    __shared__ unsigned lvrk[WSTEPS];            // 32 KB: rank<<8 | level
    __shared__ int lcnt[MAXR * NSG];             // 6 KB
    __shared__ unsigned lvpk[MAXR], wvbase[MAXR];
    __shared__ unsigned char serf[MAXR];
    __shared__ int nlvlsh;
    __shared__ unsigned totpk;
    __shared__ int ucnt4[WVN], sbase4[WVN];

    unsigned* tbl   = pool;
    unsigned* spair = pool + DIM;

    const int b    = blockIdx.x;
    const int walk = b / NW2;
    const int w    = b % NW2;
    const int t    = threadIdx.x;
    const int gb   = w * WSTEPS;
    const int sg   = t >> 6;

    const int*   I = walk ? i2 : i1;
    const int*   J = walk ? j2 : j1;
    const float* C = walk ? c2 : c1;
    const float* S = walk ? s2 : s1;

    uint4* slotp = recs + (size_t)b * SLOTREC;

    for (int s = t; s < WSTEPS; s += KT)
        spair[s] = (unsigned)I[gb + s] | ((unsigned)J[gb + s] << 16);
    for (int k = t; k < DIM; k += KT) tbl[k] = 0xFFFFFFFFu;
    for (int k = t; k < MAXR * NSG; k += KT) lcnt[k] = 0;
    if (t < MAXR) serf[t] = 0;
    if (t == 0) nlvlsh = 1;
    __syncthreads();

    // ---- election: 2 barriers/round; level = DAG depth --------------------
    unsigned pmask = (1u << SPT) - 1u;
    for (int rr = 0; rr < MAXR; ++rr) {
        const unsigned rk = (unsigned)(MAXR - 1 - rr) << 13;
#pragma unroll
        for (int q = 0; q < SPT; ++q)
            if (pmask & (1u << q)) {
                const int s = q * KT + t;
                const unsigned sp = spair[s];
                const unsigned key = rk | (unsigned)s;
                atomicMin(&tbl[sp & 0xFFFFu], key);
                atomicMin(&tbl[sp >> 16], key);
            }
        __syncthreads();
#pragma unroll
        for (int q = 0; q < SPT; ++q)
            if (pmask & (1u << q)) {
                const int s = q * KT + t;
                const unsigned sp = spair[s];
                const unsigned key = rk | (unsigned)s;
                if (tbl[sp & 0xFFFFu] == key && tbl[sp >> 16] == key) {
                    const int rank = atomicAdd(&lcnt[rr * NSG + sg], 1);
                    lvrk[s] = ((unsigned)rank << 8) | (unsigned)rr;
                    pmask &= ~(1u << q);
                }
            }
        const int np = __syncthreads_count(pmask != 0);
        if (np == 0) break;
    }
#pragma unroll
    for (int q = 0; q < SPT; ++q)
        if (pmask & (1u << q)) {
            const int s = q * KT + t;
            const int rank = atomicAdd(&lcnt[(MAXR - 1) * NSG + sg], 1);
            lvrk[s] = ((unsigned)rank << 8) | (unsigned)(MAXR - 1);
        }
    __syncthreads();

    // ---- layout: per-level per-wave chunk streams; small levels serial ----
    if (t < MAXR) {
        int run = 0;
        for (int g = 0; g < NSG; ++g) {
            const int v = lcnt[t * NSG + g];
            lcnt[t * NSG + g] = run;
            run += v;
        }
        const int nch = (run + 127) >> 7;
        unsigned pk = 0;
        if (run > 0 && nch <= 2) { serf[t] = 1; pk = (unsigned)nch; }
        else {
#pragma unroll
            for (int wv = 0; wv < WVN; ++wv)
                pk |= (unsigned)((nch + (WVN - 1 - wv)) >> 2) << (8 * wv);
        }
        lvpk[t] = pk;
        if (run > 0) atomicMax(&nlvlsh, t + 1);
    }
    __syncthreads();
    if (t < 64) {
        const int l = t;
        const unsigned w1 = lvpk[l];
        unsigned x1 = w1;
        for (int off = 1; off < 64; off <<= 1) {
            const unsigned v = (unsigned)__shfl_up((int)x1, off);
            if (l >= off) x1 += v;
        }
        wvbase[l] = x1 - w1;
        const unsigned seg1 = (unsigned)__shfl((int)x1, 63);
        const int l2 = 64 + (l & 31);
        const unsigned w2 = lvpk[l2];
        unsigned x2 = w2;
        for (int off = 1; off < 32; off <<= 1) {
            const unsigned v = (unsigned)__shfl_up((int)x2, off);
            if ((l & 31) >= off) x2 += v;
        }
        if (l < 32) wvbase[l2] = seg1 + x2 - w2;
        if (l == 31) totpk = seg1 + x2;          // per-wave used chunk totals
    }
    __syncthreads();
    if (t < WVN) {
        int u = (int)((totpk >> (8 * t)) & 0xFFu);
        ucnt4[t] = (u > PWC) ? PWC : u;
    }
    if (t < MAXR - 1) {
        if (serf[t] && serf[t + 1]) lvpk[t] |= 0x80000000u;
    }
    __syncthreads();
    if (t == 0) {
        sbase4[0] = 0;
        for (int v = 1; v < WVN; ++v) sbase4[v] = sbase4[v - 1] + ucnt4[v - 1];
        nlvls[b] = nlvlsh;
    }
    if (t < MAXR) lvmeta_g[b * MAXR + t] = lvpk[t];
    __syncthreads();

    // ---- inv table over used positions (reuses pool; spair now dead) ------
    const int usedtot = sbase4[WVN - 1] + ucnt4[WVN - 1];     // chunks
    for (int k = t; k < usedtot * 64; k += KT) pool[k] = 0xFFFFFFFFu;
    __syncthreads();
    unsigned short* inv = (unsigned short*)pool;
#pragma unroll
    for (int q = 0; q < SPT; ++q) {
        const int s = q * KT + t;
        const unsigned v = lvrk[s];
        const int lvl  = (int)(v & 0xFFu);
        const int rank = (int)(v >> 8) + lcnt[lvl * NSG + sg];
        const int cl   = rank >> 7;
        const int pos  = rank & 127;
        int wv2, wc2;
        if (serf[lvl]) { wv2 = 0; wc2 = cl; }
        else           { wv2 = cl & (WVN - 1); wc2 = cl >> 2; }
        const int pch = (int)((wvbase[lvl] >> (8 * wv2)) & 0xFFu) + wc2;
        if (pch < ucnt4[wv2]) {
            const int ipos = (sbase4[wv2] + pch) * 128 + pos;
            if (ipos < INVCAP) inv[ipos] = (unsigned short)s;
        }
    }
    __syncthreads();

    // ---- coalesced exact emission (real record or identity pad) -----------
    const uint4 padrec = { (unsigned)(PADI * 8), 0x3F800000u, 0u, (unsigned)(PADJ * 8) };
    for (int wv = 0; wv < WVN; ++wv) {
        const int npos = ucnt4[wv] * 128;
        const int ibase = sbase4[wv] * 128;
        uint4* dst = slotp + (size_t)wv * (PWC * CHUNK);
        for (int p = t; p < npos; p += KT) {
            const unsigned s = inv[ibase + p];
            uint4 r = padrec;
            if (s != 0xFFFFu) {
                const int g = gb + (int)s;
                r.x = (unsigned)(I[g] * 8);
                r.y = __builtin_bit_cast(unsigned, C[g]);
                r.z = __builtin_bit_cast(unsigned, S[g]);
                r.w = (unsigned)(J[g] * 8);
            }
            dst[p] = r;
        }
    }
}

// ---------------------------------------------------------------------------
// walk body (shared by kboth path and fallback kernel)
// ---------------------------------------------------------------------------
__device__ void walk_body(char* smem, int pr,
                          const float* __restrict__ X, const float* __restrict__ vec,
                          const uint4* __restrict__ recs, const int* __restrict__ nlvls,
                          const unsigned* __restrict__ lvmeta_g,
                          float* __restrict__ dstbuf, int directadd) {
    float2* rw = (float2*)smem;
    unsigned* lvm = (unsigned*)(smem + (DIM + 2) * 8);
    const int tid  = threadIdx.x;
    const int wv   = tid >> 6;
    const int lane = tid & 63;
    const int rA   = pr * 2, rB = pr * 2 + 1;

    {
        const float4* xa = (const float4*)(X + (size_t)rA * DIM);
        const float4* xb = (const float4*)(X + (size_t)rB * DIM);
        for (int c4 = tid; c4 < DIM / 4; c4 += 256) {
            const float4 a = xa[c4], b = xb[c4];
            rw[c4 * 4 + 0] = make_float2(a.x, b.x);
            rw[c4 * 4 + 1] = make_float2(a.y, b.y);
            rw[c4 * 4 + 2] = make_float2(a.z, b.z);
            rw[c4 * 4 + 3] = make_float2(a.w, b.w);
        }
        if (tid < 2) rw[DIM + tid] = make_float2(0.f, 0.f);
    }

    for (int slot = 0; slot < NSLOT; ++slot) {
        if (slot == NW2) {
            __syncthreads();
            const float4* v4 = (const float4*)vec;
            for (int c4 = tid; c4 < DIM / 4; c4 += 256) {
                const float4 v = v4[c4];
#pragma unroll
                for (int q = 0; q < 4; ++q) {
                    float2 tv = rw[c4 * 4 + q];
                    const float sc = (q == 0) ? v.x : (q == 1) ? v.y : (q == 2) ? v.z : v.w;
                    tv.x *= sc; tv.y *= sc;
                    rw[c4 * 4 + q] = tv;
                }
            }
        }
        if (tid < MAXR) lvm[tid] = lvmeta_g[slot * MAXR + tid];
        const int nlvl = nlvls[slot];
        __syncthreads();

        const uint4* wbase = recs + (size_t)slot * SLOTREC + (size_t)wv * (PWC * CHUNK);
        uint4 r0A = wbase[lane],       r0B = wbase[64 + lane];
        uint4 r1A = wbase[128 + lane], r1B = wbase[192 + lane];
        uint4 r2A = wbase[256 + lane], r2B = wbase[320 + lane];
        int t = 0;

        for (int lvl = 0; lvl < nlvl; ++lvl) {
            const unsigned mm = lvm[lvl];
            int n = (int)((mm >> (wv * 8)) & 0xFFu);
            if (wv == 3) n &= 0x7F;
            for (int it = 0; it < n; ++it) {
                int kc = t + 3; if (kc > PWC - 1) kc = PWC - 1;
                const uint4 mA = wbase[(size_t)kc * CHUNK + lane];
                const uint4 mB = wbase[(size_t)kc * CHUNK + 64 + lane];

                const int   ia = (int)r0A.x, ja = (int)r0A.w;
                const int   ib = (int)r0B.x, jb = (int)r0B.w;
                const float ca = bitf(r0A.y), sa = bitf(r0A.z);
                const float cb = bitf(r0B.y), sb = bitf(r0B.z);
                const float2 gai = ldrw(rw, ia), gaj = ldrw(rw, ja);
                const float2 gbi = ldrw(rw, ib), gbj = ldrw(rw, jb);

                float2 wia, wja, wib, wjb;
                wia.x = fmaf(ca, gai.x,  sa * gaj.x);
                wia.y = fmaf(ca, gai.y,  sa * gaj.y);
                wja.x = fmaf(ca, gaj.x, -sa * gai.x);
                wja.y = fmaf(ca, gaj.y, -sa * gai.y);
                wib.x = fmaf(cb, gbi.x,  sb * gbj.x);
                wib.y = fmaf(cb, gbi.y,  sb * gbj.y);
                wjb.x = fmaf(cb, gbj.x, -sb * gbi.x);
                wjb.y = fmaf(cb, gbj.y, -sb * gbi.y);
                strw(rw, ia, wia); strw(rw, ja, wja);
                strw(rw, ib, wib); strw(rw, jb, wjb);

                r0A = r1A; r0B = r1B;
                r1A = r2A; r1B = r2B;
                r2A = mA;  r2B = mB;
                ++t;
            }
            if (!(mm & 0x80000000u)) {
                __builtin_amdgcn_sched_barrier(0);
                asm volatile("s_waitcnt lgkmcnt(0)" ::: "memory");
                __builtin_amdgcn_s_barrier();
                __builtin_amdgcn_sched_barrier(0);
            }
        }
    }

    float4* oa = (float4*)(dstbuf + (size_t)rA * DIM);
    float4* ob = (float4*)(dstbuf + (size_t)rB * DIM);
    for (int c4 = tid; c4 < DIM / 4; c4 += 256) {
        const float2 p0 = rw[c4 * 4 + 0], p1 = rw[c4 * 4 + 1];
        const float2 p2 = rw[c4 * 4 + 2], p3 = rw[c4 * 4 + 3];
        float4 ta, tb;
        if (directadd) { ta = oa[c4]; tb = ob[c4]; }
        else           { ta = (float4){0,0,0,0}; tb = (float4){0,0,0,0}; }
        ta.x += p0.x; ta.y += p1.x; ta.z += p2.x; ta.w += p3.x;
        tb.x += p0.y; tb.y += p1.y; tb.z += p2.y; tb.w += p3.y;
        oa[c4] = ta; ob[c4] = tb;
    }
}

// ---------------------------------------------------------------------------
// GEMM body (bf16, global_load_lds staging, BK=64)
// ---------------------------------------------------------------------------
__device__ void gemm_body(char* smem, int bid,
                          const short* __restrict__ Xb, const short* __restrict__ Wb,
                          const float* __restrict__ bias, float* __restrict__ out,
                          float* __restrict__ parts, int nks) {
    short* As = (short*)smem;
    short* Bs = As + 128 * 64;
    const int ks   = bid % nks;
    const int tile = bid / nks;
    const int bm   = (tile >> 5) * 128;
    const int bn   = (tile & 31) * 128;
    const int tid  = threadIdx.x;
    const int lane = tid & 63;
    const int wv   = tid >> 6;
    const int wr   = (wv >> 1) * 64;
    const int wc   = (wv & 1) * 64;
    const int fr   = lane & 15;
    const int ke   = (lane >> 4) * 8;

    f32x4 acc[4][4];
#pragma unroll
    for (int m = 0; m < 4; ++m)
#pragma unroll
        for (int n = 0; n < 4; ++n) acc[m][n] = (f32x4){0.f, 0.f, 0.f, 0.f};

    const int lrow = lane >> 3;
    const int scol = (((lane & 7) ^ (lrow & 7)) << 3);
    const short* gx = Xb + (size_t)(bm + wv * 32 + lrow) * DIM + scol;
    const short* gw = Wb + (size_t)(bn + wv * 32 + lrow) * DIM + scol;
    short* lA = As + wv * 2048;
    short* lB = Bs + wv * 2048;

    const int nkt   = (DIM / 64) / nks;
    const int kbase = ks * (DIM / nks);
    for (int kt = 0; kt < nkt; ++kt) {
        const int k0 = kbase + kt * 64;
        __syncthreads();
#pragma unroll
        for (int q = 0; q < 4; ++q) {
            gl16(gx + (size_t)(q * 8) * DIM + k0, lA + q * 512);
            gl16(gw + (size_t)(q * 8) * DIM + k0, lB + q * 512);
        }
        __syncthreads();
#pragma unroll
        for (int kk = 0; kk < 64; kk += 32) {
            const int sb = (kk + ke) >> 3;
            short8 af[4], bf[4];
#pragma unroll
            for (int m = 0; m < 4; ++m) {
                const int R = wr + m * 16 + fr;
                af[m] = *(const short8*)&As[R * 64 + ((sb ^ (R & 7)) << 3)];
            }
#pragma unroll
            for (int n = 0; n < 4; ++n) {
                const int R = wc + n * 16 + fr;
                bf[n] = *(const short8*)&Bs[R * 64 + ((sb ^ (R & 7)) << 3)];
            }
#pragma unroll
            for (int m = 0; m < 4; ++m)
#pragma unroll
                for (int n = 0; n < 4; ++n)
                    acc[m][n] = __builtin_amdgcn_mfma_f32_16x16x32_bf16(
                        __builtin_bit_cast(bf16x8, af[m]),
                        __builtin_bit_cast(bf16x8, bf[n]),
                        acc[m][n], 0, 0, 0);
        }
    }
    float* dst = ks ? (parts + (size_t)(ks - 1) * ROWS * DIM) : out;
#pragma unroll
    for (int n = 0; n < 4; ++n) {
        const int col = bn + wc + n * 16 + fr;
        const float bv = ks ? 0.f : bias[col];
#pragma unroll
        for (int m = 0; m < 4; ++m) {
            const int rbase = bm + wr + m * 16 + (lane >> 4) * 4;
#pragma unroll
            for (int r = 0; r < 4; ++r)
                dst[(size_t)(rbase + r) * DIM + col] = acc[m][n][r] + bv;
        }
    }
}

// ---------------------------------------------------------------------------
// 2) kboth: walk (blocks 0..255) + GEMM (blocks 256..) in one launch
// ---------------------------------------------------------------------------
__global__ __launch_bounds__(256) void kboth(
    const float* __restrict__ X, const float* __restrict__ vec,
    const uint4* __restrict__ recs, const int* __restrict__ nlvls,
    const unsigned* __restrict__ lvmeta_g, float* __restrict__ walkbuf,
    const short* __restrict__ Xb, const short* __restrict__ Wb,
    const float* __restrict__ bias, float* __restrict__ out,
    float* __restrict__ parts, int nks) {
    __shared__ __align__(16) char smem[SMEMB];
    if (blockIdx.x < ROWS / 2)
        walk_body(smem, blockIdx.x, X, vec, recs, nlvls, lvmeta_g, walkbuf, 0);
    else
        gemm_body(smem, blockIdx.x - ROWS / 2, Xb, Wb, bias, out, parts, nks);
}

// ---------------------------------------------------------------------------
// 3) kadd: out += walkbuf + sum(parts)
// ---------------------------------------------------------------------------
__global__ __launch_bounds__(256) void kadd(float* __restrict__ out,
                                            const float* __restrict__ walkbuf,
                                            const float* __restrict__ parts, int nparts) {
    const size_t N = (size_t)ROWS * DIM / 4;
    const size_t i0 = (size_t)blockIdx.x * 256 + threadIdx.x;
    float4* o4 = (float4*)out;
    const float4* w4 = (const float4*)walkbuf;
    const float4* p4 = (const float4*)parts;
    for (size_t i = i0; i < N; i += (size_t)gridDim.x * 256) {
        float4 t = o4[i];
        const float4 s = w4[i];
        t.x += s.x; t.y += s.y; t.z += s.z; t.w += s.w;
        for (int p = 0; p < nparts; ++p) {
            const float4 a = p4[i + (size_t)p * N];
            t.x += a.x; t.y += a.y; t.z += a.z; t.w += a.w;
        }
        o4[i] = t;
    }
}

// ---------------------------------------------------------------------------
// fallback kernels (small workspace): fp32-staging GEMM + direct-add walk
// ---------------------------------------------------------------------------
#define LDT 72
__global__ __launch_bounds__(256) void kgemm_small(const float* __restrict__ X, const float* __restrict__ W,
                                                   const float* __restrict__ bias, float* __restrict__ out) {
    __shared__ short As[64 * LDT];
    __shared__ short Bs[128 * LDT];
    const int tid  = threadIdx.x;
    const int bn   = (blockIdx.x & 31) * 128;
    const int bm   = (blockIdx.x >> 5) * 64;
    const int lane = tid & 63;
    const int wv   = tid >> 6;
    const int wr   = (wv >> 1) * 32;
    const int wc   = (wv & 1) * 64;
    const int fr   = lane & 15;
    const int ke   = (lane >> 4) * 8;

    f32x4 acc[2][4];
#pragma unroll
    for (int m = 0; m < 2; ++m)
#pragma unroll
        for (int n = 0; n < 4; ++n) acc[m][n] = (f32x4){0.f, 0.f, 0.f, 0.f};

    const int tr = tid >> 2;
    const int tc = (tid & 3) << 4;

    for (int kt = 0; kt < DIM / 64; ++kt) {
        const int k0 = kt * 64;
        float4 ra[4], rb[2][4];
        {
            const float4* ga = (const float4*)(X + (size_t)(bm + tr) * DIM + k0 + tc);
#pragma unroll
            for (int q = 0; q < 4; ++q) ra[q] = ga[q];
#pragma unroll
            for (int h = 0; h < 2; ++h) {
                const float4* gw = (const float4*)(W + (size_t)(bn + h * 64 + tr) * DIM + k0 + tc);
#pragma unroll
                for (int q = 0; q < 4; ++q) rb[h][q] = gw[q];
            }
        }
        __syncthreads();
        *(short8*)&As[tr * LDT + tc]     = pack8(ra[0], ra[1]);
        *(short8*)&As[tr * LDT + tc + 8] = pack8(ra[2], ra[3]);
#pragma unroll
        for (int h = 0; h < 2; ++h) {
            *(short8*)&Bs[(h * 64 + tr) * LDT + tc]     = pack8(rb[h][0], rb[h][1]);
            *(short8*)&Bs[(h * 64 + tr) * LDT + tc + 8] = pack8(rb[h][2], rb[h][3]);
        }
        __syncthreads();
#pragma unroll
        for (int kk = 0; kk < 64; kk += 32) {
            short8 af[2], bf[4];
#pragma unroll
            for (int m = 0; m < 2; ++m)
                af[m] = *(const short8*)&As[(wr + m * 16 + fr) * LDT + kk + ke];
#pragma unroll
            for (int n = 0; n < 4; ++n)
                bf[n] = *(const short8*)&Bs[(wc + n * 16 + fr) * LDT + kk + ke];
#pragma unroll
            for (int m = 0; m < 2; ++m)
#pragma unroll
                for (int n = 0; n < 4; ++n)
                    acc[m][n] = __builtin_amdgcn_mfma_f32_16x16x32_bf16(
                        __builtin_bit_cast(bf16x8, af[m]),
                        __builtin_bit_cast(bf16x8, bf[n]),
                        acc[m][n], 0, 0, 0);
        }
    }
#pragma unroll
    for (int n = 0; n < 4; ++n) {
        const int col = bn + wc + n * 16 + fr;
        const float bv = bias[col];
#pragma unroll
        for (int m = 0; m < 2; ++m) {
            const int rbase = bm + wr + m * 16 + (lane >> 4) * 4;
#pragma unroll
            for (int r = 0; r < 4; ++r)
                out[(size_t)(rbase + r) * DIM + col] = acc[m][n][r] + bv;
        }
    }
}

__global__ __launch_bounds__(256) void kwalk_fb(const float* __restrict__ X, const float* __restrict__ vec,
                                                const uint4* __restrict__ recs, const int* __restrict__ nlvls,
                                                const unsigned* __restrict__ lvmeta_g,
                                                float* __restrict__ out) {
    __shared__ __align__(16) char smem[SMEMB];
    walk_body(smem, blockIdx.x, X, vec, recs, nlvls, lvmeta_g, out, 1);
}

// ---------------------------------------------------------------------------
extern "C" void kernel_launch(void* const* d_in, const int* in_sizes, int n_in,
                              void* d_out, int out_size, void* d_ws, size_t ws_size,
                              hipStream_t stream) {
    const float* X    = (const float*)d_in[0];
    const float* W    = (const float*)d_in[1];
    const float* bias = (const float*)d_in[2];
    const float* vec  = (const float*)d_in[3];
    const int*   i1   = (const int*)d_in[4];
    const int*   j1   = (const int*)d_in[5];
    const float* c1   = (const float*)d_in[6];
    const float* s1   = (const float*)d_in[7];
    const int*   i2   = (const int*)d_in[8];
    const int*   j2   = (const int*)d_in[9];
    const float* c2   = (const float*)d_in[10];
    const float* s2   = (const float*)d_in[11];
    float* out = (float*)d_out;

    const size_t RD         = (size_t)ROWS * DIM * 4;            // 8 MiB
    const size_t WBB        = (size_t)DIM * DIM * 2;             // 32 MiB
    const size_t XBB        = (size_t)ROWS * DIM * 2;            // 4 MiB
    const size_t recs_bytes = (size_t)NSLOT * SLOTREC * 16;      // 9.44 MiB
    const size_t off_lvm    = recs_bytes + 1024;
    const size_t off_parts  = recs_bytes + 16384;

    int nks = 0;
    size_t off_wb = 0;
    {
        const size_t need4 = off_parts + 3 * RD + WBB + XBB + RD;
        const size_t need2 = off_parts + 1 * RD + WBB + XBB + RD;
        if      (ws_size >= need4) { nks = 4; off_wb = off_parts + 3 * RD; }
        else if (ws_size >= need2) { nks = 2; off_wb = off_parts + 1 * RD; }
    }

    uint4*    recs   = (uint4*)d_ws;
    int*      nlvlsb = (int*)((char*)d_ws + recs_bytes);
    unsigned* lvmeta = (unsigned*)((char*)d_ws + off_lvm);
    float*    parts  = (float*)((char*)d_ws + off_parts);
    short*    wbuf   = (short*)((char*)d_ws + off_wb);
    short*    xbuf   = (short*)((char*)d_ws + off_wb + WBB);
    float*    wkbuf  = (float*)((char*)d_ws + off_wb + WBB + XBB);
    const bool bf = (nks > 0);

    hipLaunchKernelGGL(kfused, dim3(NSLOT + (bf ? (NCVW + NCVX) : 0)), dim3(KT), 0, stream,
                       i1, j1, c1, s1, i2, j2, c2, s2, recs, nlvlsb, lvmeta,
                       bf ? 1 : 0, W, X, wbuf, xbuf);
    if (bf) {
        hipLaunchKernelGGL(kboth, dim3(ROWS / 2 + 128 * nks), dim3(256), 0, stream,
                           X, vec, recs, nlvlsb, lvmeta, wkbuf,
                           xbuf, wbuf, bias, out, parts, nks);
        hipLaunchKernelGGL(kadd, dim3(512), dim3(256), 0, stream,
                           out, wkbuf, parts, nks - 1);
    } else {
        hipLaunchKernelGGL(kgemm_small, dim3(256), dim3(256), 0, stream, X, W, bias, out);
        hipLaunchKernelGGL(kwalk_fb, dim3(ROWS / 2), dim3(256), 0, stream,
                           X, vec, recs, nlvlsb, lvmeta, out);
    }
}